// Round 1
// baseline (298.230 us; speedup 1.0000x reference)
//
#include <hip/hip_runtime.h>
#include <hip/hip_bf16.h>

#define BB 20
#define SS 500
#define DIMD 300
#define HIDH 600
#define QKD 128

typedef unsigned short u16;
typedef __attribute__((ext_vector_type(8))) __bf16 bf16x8;
typedef __attribute__((ext_vector_type(8))) short short8;
typedef __attribute__((ext_vector_type(4))) float floatx4;

__device__ __forceinline__ u16 f2bu(float f) {
    __hip_bfloat16 h = __float2bfloat16(f);
    return *reinterpret_cast<u16*>(&h);
}
__device__ __forceinline__ float bu2f(u16 u) {
    unsigned v = ((unsigned)u) << 16;
    return __uint_as_float(v);
}

__device__ __forceinline__ floatx4 mfma_bf16(short8 a, short8 b, floatx4 c) {
    return __builtin_amdgcn_mfma_f32_16x16x32_bf16(
        __builtin_bit_cast(bf16x8, a), __builtin_bit_cast(bf16x8, b), c, 0, 0, 0);
}

// async global->LDS, 16B/lane; LDS dest = wave-uniform base + lane*16
__device__ __forceinline__ void glds16(const u16* g, u16* l) {
    __builtin_amdgcn_global_load_lds(
        (__attribute__((address_space(1))) const void*)g,
        (__attribute__((address_space(3))) void*)l, 16, 0, 0);
}

// ---------------- merged prep + LayerNorm/shift ----------------
__global__ __launch_bounds__(256)
void prep_ln_kernel(const float* __restrict__ x, const float* __restrict__ lng,
                    const float* __restrict__ lnb, u16* __restrict__ nxb,
                    const float* __restrict__ Wh, const float* __restrict__ Wqk,
                    const float* __restrict__ Wout, const float* __restrict__ rel_emb,
                    u16* __restrict__ WhT, u16* __restrict__ Wqkb,
                    u16* __restrict__ WoutT, float* __restrict__ bias,
                    int* __restrict__ hist, unsigned* __restrict__ gmaxu) {
    long id = (long)blockIdx.x * 256 + threadIdx.x;
    if (id < 640000) {                        // LayerNorm + shift, one wave per row
        int bs = id >> 6;
        int t = id & 63;
        int s = bs % SS;
        const float* xr = x + (long)bs * DIMD;
        float sum = 0.f, sq = 0.f;
        for (int d = t; d < DIMD; d += 64) { float v = xr[d]; sum += v; sq += v * v; }
        for (int off = 1; off < 64; off <<= 1) {
            sum += __shfl_xor(sum, off);
            sq  += __shfl_xor(sq, off);
        }
        float mean = sum * (1.f / DIMD);
        float var  = sq * (1.f / DIMD) - mean * mean;
        float rstd = rsqrtf(var + 1e-5f);
        for (int d = t; d < DIMD; d += 64) {
            float nv = (xr[d] - mean) * rstd * lng[d] + lnb[d];
            if (d < DIMD / 2) {
                if (s < SS - 1) nxb[(long)(bs + 1) * 320 + d] = f2bu(nv);
            } else {
                nxb[(long)bs * 320 + d] = f2bu(nv);
            }
        }
        if (s == 0)
            for (int d = t; d < DIMD / 2; d += 64) nxb[(long)bs * 320 + d] = 0;
        for (int d = DIMD + t; d < 320; d += 64) nxb[(long)bs * 320 + d] = 0;
        return;
    }
    id -= 640000;
    if (id < 384000) {                        // WhT[n][k], k<320
        int k = id / 1200, n = id - (long)k * 1200;
        WhT[(long)n * 320 + k] = (k < 300) ? f2bu(Wh[(long)k * 1200 + n]) : (u16)0;
        return;
    }
    id -= 384000;
    if (id < 40960) {                         // Wqkb[n][k]
        int k = id / 128, n = id - (long)k * 128;
        Wqkb[(long)n * 320 + k] = (k < 300) ? f2bu(Wqk[(long)k * 128 + n]) : (u16)0;
        return;
    }
    id -= 40960;
    if (id < 182400) {                        // WoutT[n][k], k<608
        int k = id / 300, n = id - (long)k * 300;
        WoutT[(long)n * 608 + k] = (k < 600) ? f2bu(Wout[(long)k * 300 + n]) : (u16)0;
        return;
    }
    id -= 182400;
    if (id < 250000) {                        // T5 bias 500x500
        int i = id / 500, j = id - (long)i * 500;
        int n = i - j;
        int ret = (n < 0) ? 16 : 0;
        int na = n < 0 ? -n : n;
        int bucket;
        if (na < 8) bucket = ret + na;
        else {
            int vil = 8 + (int)(logf((float)na * 0.125f) / logf(16.f) * 8.f);
            vil = vil < 15 ? vil : 15;
            bucket = ret + vil;
        }
        bias[id] = rel_emb[bucket] * 11.313708498984761f;
        return;
    }
    id -= 250000;
    if (id < 5120) { hist[id] = 0; return; }   // 20 batches x 256-int stride
    id -= 5120;
    if (id < 1280) gmaxu[id] = 0u;             // 20 batches x 64-uint stride
}

// ---------------- Epilogues ----------------
struct EpiH {            // gemm1 transposed: m = hidden [0,1200), n = token [0,10000)
    const float* bh; u16* vT; float* gateT;
    __device__ void operator()(float acc, int bz, int m, int n) const {
        if (m >= 1200 || n >= 10000) return;
        float v = acc + bh[m];
        v = v / (1.f + expf(-v));
        int b = n / SS, s = n - b * SS;
        if (m < HIDH) vT[((long)b * 640 + m) * 512 + s] = f2bu(v);
        else gateT[((long)b * HIDH + (m - HIDH)) * SS + s] = v;
    }
};
struct EpiQKRot {        // qk + silu + gamma/beta + rotary (NO early return: shuffles)
    const float* bqk; const float* gamma; const float* beta;
    u16* qb; u16* kb;
    __device__ void operator()(float acc, int bz, int m, int n) const {
        float v = acc + bqk[n];
        v = v / (1.f + expf(-v));
        float qp = v * gamma[n] + beta[n];
        float kp = v * gamma[QKD + n] + beta[QKD + n];
        float qx = __shfl_xor(qp, 1);
        float kx = __shfl_xor(kp, 1);
        float qo = qp, ko = kp;
        if (n < 32) {
            int s = m % SS;
            float inv = expf(-(float)(n & ~1) * (logf(10000.f) / 32.f));
            float ang = (float)s * inv;
            float c, sn;
            sincosf(ang, &sn, &c);
            float qr = (n & 1) ? qx : -qx;
            float kr = (n & 1) ? kx : -kx;
            qo = qp * c + qr * sn;
            ko = kp * c + kr * sn;
        }
        if (m < 10000) {
            qb[(long)m * QKD + n] = f2bu(qo);
            kb[(long)m * QKD + n] = f2bu(ko);
        }
    }
};
struct EpiAttnB {        // scores -> (relu((s+bias)/S))^2 * mask -> bf16 [500][512]
    const float* bias; const float* mask; u16* attnb;
    __device__ void operator()(float acc, int b, int m, int n) const {
        if (m >= SS || n >= 512) return;
        float r = 0.f;
        if (n < SS) {
            float s = (acc + bias[m * SS + n]) * (1.f / (float)SS);
            s = fmaxf(s, 0.f);
            r = s * s * mask[m * SS + n];
        }
        attnb[((long)b * SS + m) * 512 + n] = f2bu(r);
    }
};
struct EpiGateN {        // gated = gm * (attn@v) * gate -> bf16 [10000][608]
    const u16* gateNb; const int* counts; const int* t2v; u16* gated;
    __device__ void operator()(float acc, int b, int m, int n) const {
        if (m >= SS || n >= 608) return;
        float r = 0.f;
        if (n < HIDH) {
            float g = bu2f(gateNb[((long)b * SS + m) * HIDH + n]);
            int c = counts[(b * 100 + m / 5) * 120 + n / 5];
            float bv = (c >= t2v[b]) ? 1.f : 0.25f;
            float p = ((m % 5) == 4 || (n % 5) == 4) ? 0.f : 1.f;
            r = acc * g * bv * p;
        }
        gated[((long)(b * SS + m)) * 608 + n] = f2bu(r);
    }
};
struct EpiOutB {         // out = gated@Wout + bout + x
    const float* bout; const float* x; float* out;
    __device__ void operator()(float acc, int b, int m, int n) const {
        if (m >= 10000 || n >= DIMD) return;
        out[(long)m * DIMD + n] = acc + bout[n] + x[(long)m * DIMD + n];
    }
};

// ---------------- barrier-free bf16 MFMA GEMM (4-wave 32x32/wave variant) ----------------
// Kept for the small/shallow GEMMs (qk, scores, out) where block count is too
// low for the 1-wave kernel to keep enough waves/CU resident.
template<int MODE, class Epi>
__global__ __launch_bounds__(256)
void gemm_nb(const u16* __restrict__ A, const u16* __restrict__ Bt,
             int Kp, int lda, int ldb, long sA, long sB,
             int TX, int TY, int bound, Epi epi) {
    int lin = blockIdx.x;
    int xcd = lin & 7, i = lin >> 3;
    int per = TX * TY;
    int w = i / per;
    int tl = i - w * per;
    int g = xcd + (w << 3);
    int tx = tl % TX, ty = tl / TX;
    int bx, by, bz;
    if (MODE == 0)      { if (g >= bound) return; bx = tx; by = ty; bz = g; }
    else if (MODE == 1) { bx = g * TX + tx; if (bx >= bound) return; by = ty; bz = 0; }
    else                { by = g * TY + ty; if (by >= bound) return; bx = tx; bz = 0; }

    A += (long)bz * sA; Bt += (long)bz * sB;
    int t = threadIdx.x, lane = t & 63, wave = t >> 6;
    int l15 = lane & 15, l4 = lane >> 4;
    int m0 = (by << 6) + ((wave >> 1) << 5);
    int n0 = (bx << 6) + ((wave & 1) << 5);

    // [wave][buf][row 0..31=A,32..63=B][k32] ; unpadded 64B rows (glds contract)
    __shared__ __align__(16) u16 S[4][2][64][32];

    int srow = lane >> 2, scol = (lane & 3) << 3;
    const u16* agp0 = A + (long)(m0 + srow) * lda + scol;
    const u16* agp1 = A + (long)(m0 + 16 + srow) * lda + scol;
    const u16* bgp0 = Bt + (long)(n0 + srow) * ldb + scol;
    const u16* bgp1 = Bt + (long)(n0 + 16 + srow) * ldb + scol;

    floatx4 acc[2][2];
#pragma unroll
    for (int i2 = 0; i2 < 2; ++i2)
#pragma unroll
        for (int j = 0; j < 2; ++j) acc[i2][j] = (floatx4){0.f, 0.f, 0.f, 0.f};

    // prologue stage into buf 0 (4 outstanding)
    glds16(agp0, &S[wave][0][0][0]);
    glds16(agp1, &S[wave][0][16][0]);
    glds16(bgp0, &S[wave][0][32][0]);
    glds16(bgp1, &S[wave][0][48][0]);

    for (int k0 = 0; k0 < Kp; k0 += 32) {
        int buf = (k0 >> 5) & 1;
        int kn = k0 + 32;
        if (kn < Kp) {                       // prefetch next into back buffer
            int nb = buf ^ 1;
            glds16(agp0 + kn, &S[wave][nb][0][0]);
            glds16(agp1 + kn, &S[wave][nb][16][0]);
            glds16(bgp0 + kn, &S[wave][nb][32][0]);
            glds16(bgp1 + kn, &S[wave][nb][48][0]);
            // wait ONLY for current buf's 4 loads; prefetch stays in flight
            asm volatile("s_waitcnt vmcnt(4)" ::: "memory");
        } else {
            asm volatile("s_waitcnt vmcnt(0)" ::: "memory");
        }
        short8 a0 = *(const short8*)(&S[wave][buf][l15][l4 << 3]);
        short8 a1 = *(const short8*)(&S[wave][buf][16 + l15][l4 << 3]);
        short8 b0 = *(const short8*)(&S[wave][buf][32 + l15][l4 << 3]);
        short8 b1 = *(const short8*)(&S[wave][buf][48 + l15][l4 << 3]);
        acc[0][0] = mfma_bf16(a0, b0, acc[0][0]);
        acc[0][1] = mfma_bf16(a0, b1, acc[0][1]);
        acc[1][0] = mfma_bf16(a1, b0, acc[1][0]);
        acc[1][1] = mfma_bf16(a1, b1, acc[1][1]);
    }
#pragma unroll
    for (int i2 = 0; i2 < 2; ++i2) {
        int bm = m0 + (i2 << 4) + (l4 << 2);
#pragma unroll
        for (int j = 0; j < 2; ++j) {
            int bn = n0 + (j << 4) + l15;
#pragma unroll
            for (int r = 0; r < 4; ++r)
                epi(acc[i2][j][r], bz, bm + r, bn);
        }
    }
}

// ---------------- 1-wave 64x64 barrier-free GEMM ----------------
// Same 64x64 tile geometry and MODE/XCD mapping as gemm_nb, but ONE wave owns
// the whole tile: 4x4 acc frags, 16 MFMA per k32-step, 8 glds + 8 ds_read per
// step.  Eliminates the 2x A/B staging duplication of the 2x2-wave layout:
// half the glds bytes and half the ds_read instructions per FLOP, and 4x the
// MFMA work amortizing each vmcnt wait.  LDS 16KB/block -> 10 blocks/CU
// (10 waves/CU).  Use only where the grid has >~2000 blocks or deep K
// (h-gemm: 2983 blocks; attn@v: 1600 blocks, K=512).
// Barrier-free: per-wave private dbuf, counted s_waitcnt vmcnt(8) retires the
// current buffer's 8 loads while the 8 prefetch loads stay in flight
// (retirement is issue-ordered, m135).  Staging has NO bounds checks:
// overruns read adjacent ws buffers (finite garbage discarded by epilogue
// guards); K-pads are real zeros in memory.
template<int MODE, class Epi>
__global__ __launch_bounds__(64)
void gemm_nb1(const u16* __restrict__ A, const u16* __restrict__ Bt,
              int Kp, int lda, int ldb, long sA, long sB,
              int TX, int TY, int bound, Epi epi) {
    int lin = blockIdx.x;
    int xcd = lin & 7, i = lin >> 3;
    int per = TX * TY;
    int w = i / per;
    int tl = i - w * per;
    int g = xcd + (w << 3);
    int tx = tl % TX, ty = tl / TX;
    int bx, by, bz;
    if (MODE == 0)      { if (g >= bound) return; bx = tx; by = ty; bz = g; }
    else if (MODE == 1) { bx = g * TX + tx; if (bx >= bound) return; by = ty; bz = 0; }
    else                { by = g * TY + ty; if (by >= bound) return; bx = tx; bz = 0; }

    A += (long)bz * sA; Bt += (long)bz * sB;
    int lane = threadIdx.x;
    int l15 = lane & 15, l4 = lane >> 4;
    int m0 = by << 6, n0 = bx << 6;

    // [buf][row 0..63=A, 64..127=B][k32] ; unpadded 64B rows (glds contract)
    __shared__ __align__(16) u16 S[2][128][32];

    int srow = lane >> 2, scol = (lane & 3) << 3;
    const u16* ag[4];
    const u16* bg[4];
#pragma unroll
    for (int gi = 0; gi < 4; ++gi) {
        ag[gi] = A + (long)(m0 + gi * 16 + srow) * lda + scol;
        bg[gi] = Bt + (long)(n0 + gi * 16 + srow) * ldb + scol;
    }

    floatx4 acc[4][4];
#pragma unroll
    for (int ii = 0; ii < 4; ++ii)
#pragma unroll
        for (int j = 0; j < 4; ++j) acc[ii][j] = (floatx4){0.f, 0.f, 0.f, 0.f};

    // prologue stage into buf 0 (8 outstanding)
#pragma unroll
    for (int gi = 0; gi < 4; ++gi) glds16(ag[gi], &S[0][gi * 16][0]);
#pragma unroll
    for (int gi = 0; gi < 4; ++gi) glds16(bg[gi], &S[0][64 + gi * 16][0]);

    for (int k0 = 0; k0 < Kp; k0 += 32) {
        int buf = (k0 >> 5) & 1;
        int kn = k0 + 32;
        if (kn < Kp) {                       // prefetch next into back buffer
            int nb = buf ^ 1;
#pragma unroll
            for (int gi = 0; gi < 4; ++gi) glds16(ag[gi] + kn, &S[nb][gi * 16][0]);
#pragma unroll
            for (int gi = 0; gi < 4; ++gi) glds16(bg[gi] + kn, &S[nb][64 + gi * 16][0]);
            // wait ONLY for current buf's 8 loads; prefetch stays in flight
            asm volatile("s_waitcnt vmcnt(8)" ::: "memory");
        } else {
            asm volatile("s_waitcnt vmcnt(0)" ::: "memory");
        }
        short8 a[4], b[4];
#pragma unroll
        for (int ii = 0; ii < 4; ++ii)
            a[ii] = *(const short8*)(&S[buf][ii * 16 + l15][l4 << 3]);
#pragma unroll
        for (int j = 0; j < 4; ++j)
            b[j] = *(const short8*)(&S[buf][64 + j * 16 + l15][l4 << 3]);
#pragma unroll
        for (int ii = 0; ii < 4; ++ii)
#pragma unroll
            for (int j = 0; j < 4; ++j)
                acc[ii][j] = mfma_bf16(a[ii], b[j], acc[ii][j]);
    }
#pragma unroll
    for (int ii = 0; ii < 4; ++ii) {
        int bm = m0 + (ii << 4) + (l4 << 2);
#pragma unroll
        for (int j = 0; j < 4; ++j) {
            int bn = n0 + (j << 4) + l15;
#pragma unroll
            for (int r = 0; r < 4; ++r)
                epi(acc[ii][j][r], bz, bm + r, bn);
        }
    }
}

// ---------------- gate transpose: gateT[b][h][s] fp32 -> gateNb[b][s][h] bf16 ----------------
__global__ __launch_bounds__(256)
void gate_transpose(const float* __restrict__ gateT, u16* __restrict__ gateNb) {
    __shared__ float tile[32][33];
    int b = blockIdx.z;
    int h0 = blockIdx.x << 5, s0 = blockIdx.y << 5;
    int tx = threadIdx.x & 31, ty = threadIdx.x >> 5;
    const float* gt = gateT + (long)b * HIDH * SS;
    u16* gn = gateNb + (long)b * SS * HIDH;
    for (int r = ty; r < 32; r += 8) {
        int hh = h0 + r, ss = s0 + tx;
        if (hh < HIDH && ss < SS) tile[r][tx] = gt[(long)hh * SS + ss];
    }
    __syncthreads();
    for (int r = ty; r < 32; r += 8) {
        int ss = s0 + r, hh = h0 + tx;
        if (ss < SS && hh < HIDH) gn[(long)ss * HIDH + hh] = f2bu(tile[tx][r]);
    }
}

// ---------------- gate stats: LDS-local hist, few padded atomics ----------------
__global__ __launch_bounds__(256)
void hist_accum_kernel(const float* __restrict__ gateT, int* __restrict__ hist,
                       unsigned* __restrict__ gmaxu) {
    int b = blockIdx.y;
    const float* gb = gateT + (long)b * SS * HIDH;
    __shared__ int lh[129];
    __shared__ float wmx[4];
    for (int i = threadIdx.x; i < 129; i += 256) lh[i] = 0;
    __syncthreads();
    float lmax = -1e30f;
    int base = blockIdx.x * 2048;
#pragma unroll
    for (int e = 0; e < 8; ++e) {
        int idx = base + e * 256 + threadIdx.x;
        if (idx < SS * HIDH) {
            float g = gb[idx];
            lmax = fmaxf(lmax, g);
            float ag = fabsf(g);
            if (ag >= 1.f) {                  // hist[0] never read; >=1 is rare
                int bin = (int)fminf(floorf(ag), 128.f);
                atomicAdd(&lh[bin], 1);
            }
        }
    }
    for (int off = 32; off; off >>= 1) lmax = fmaxf(lmax, __shfl_xor(lmax, off));
    if ((threadIdx.x & 63) == 0) wmx[threadIdx.x >> 6] = lmax;
    __syncthreads();
    if (threadIdx.x == 0) {
        float m = fmaxf(fmaxf(wmx[0], wmx[1]), fmaxf(wmx[2], wmx[3]));
        unsigned bits = __float_as_uint(m);
        unsigned enc = (bits & 0x80000000u) ? ~bits : (bits | 0x80000000u);
        atomicMax(&gmaxu[b * 64], enc);       // own 256B line per batch
    }
    for (int i = threadIdx.x; i < 129; i += 256)
        if (lh[i]) atomicAdd(&hist[b * 256 + i], lh[i]);
}

// counts over gateT[h][s] with integrated per-thread trim
__global__ void counts_kernel(const float* __restrict__ gateT, const int* __restrict__ hist,
                              const unsigned* __restrict__ gmaxu, int* __restrict__ counts) {
    int id = blockIdx.x * 256 + threadIdx.x;
    if (id >= BB * 100 * 120) return;
    int b = id / 12000;
    unsigned enc = gmaxu[b * 64];
    unsigned bits = (enc & 0x80000000u) ? (enc & 0x7FFFFFFFu) : ~enc;
    float gmax = floorf(__uint_as_float(bits));
    int suffix = 0, trim = 1;
    for (int tt = 128; tt >= 1; --tt) {
        suffix += hist[b * 256 + tt];
        if ((float)tt <= gmax && suffix > 90000) { trim = tt; break; }
    }
    float tr = (float)trim;
    int r = id - b * 12000;
    int bi = r / 120, bj = r - bi * 120;
    const float* gb = gateT + (long)b * SS * HIDH;
    int c = 0;
#pragma unroll
    for (int cc = 0; cc < 4; ++cc)
#pragma unroll
        for (int rr = 0; rr < 4; ++rr) {
            float g = gb[(long)(bj * 5 + cc) * SS + bi * 5 + rr];
            c += (fabsf(g) >= tr) ? 1 : 0;
        }
    counts[id] = c;
}

__global__ __launch_bounds__(256)
void t2_kernel(const int* __restrict__ counts, int* __restrict__ t2) {
    int b = blockIdx.x;
    int t = threadIdx.x;
    __shared__ int h2[17];
    __shared__ int smax;
    if (t < 17) h2[t] = 0;
    if (t == 0) smax = 0;
    __syncthreads();
    int lmax = 0;
    for (int i = t; i < 12000; i += 256) {
        int c = counts[b * 12000 + i];
        if (c) atomicAdd(&h2[c], 1);
        lmax = lmax > c ? lmax : c;
    }
    atomicMax(&smax, lmax);
    __syncthreads();
    if (t == 0) {
        int cmax = smax;
        int suffix = 0, best = 0;
        bool found = false;
        for (int tt = 16; tt >= 1; --tt) {
            suffix += h2[tt];
            if (!found && tt <= cmax && suffix > 3600) { best = tt; found = true; }
        }
        t2[b] = found ? best : cmax;
    }
}

extern "C" void kernel_launch(void* const* d_in, const int* in_sizes, int n_in,
                              void* d_out, int out_size, void* d_ws, size_t ws_size,
                              hipStream_t stream) {
    const float* x      = (const float*)d_in[0];
    const float* mask2  = (const float*)d_in[1];
    const float* ln_g   = (const float*)d_in[2];
    const float* ln_b   = (const float*)d_in[3];
    const float* Wh     = (const float*)d_in[4];
    const float* bh     = (const float*)d_in[5];
    const float* Wqk    = (const float*)d_in[6];
    const float* bqk    = (const float*)d_in[7];
    const float* gamma  = (const float*)d_in[8];
    const float* beta   = (const float*)d_in[9];
    const float* rel_emb= (const float*)d_in[10];
    const float* Wout   = (const float*)d_in[11];
    const float* bout   = (const float*)d_in[12];
    float* out = (float*)d_out;
    float* ws  = (float*)d_ws;

    // workspace layout (float offsets; all 16B-aligned)
    float* gateT  = ws;                            //  6,000,000 f
    float* bias   = ws + 6000000;                  //    250,000 f
    u16*   nxb    = (u16*)(ws + 6250000);          // 10000x320 u16
    u16*   WhT    = (u16*)(ws + 7850000);          //  1200x320 u16
    u16*   Wqkb   = (u16*)(ws + 8042000);          //   128x320 u16
    u16*   WoutT  = (u16*)(ws + 8062480);          //   300x608 u16
    u16*   qb     = (u16*)(ws + 8153680);          // 10000x128 u16
    u16*   kb     = (u16*)(ws + 8793680);          // 10000x128 u16
    u16*   attnb  = (u16*)(ws + 9433680);          // 20x500x512 u16
    u16*   vT     = (u16*)(ws + 11993680);         // 20x640x512 u16
    u16*   gatedb = (u16*)(ws + 15270480);         // 10000x608 u16
    u16*   gateNb = (u16*)(ws + 18310480);         // 10000x600 u16
    int*   hist   = (int*)(ws + 21310480);         // 20 x 256-int stride
    unsigned* gmaxu = (unsigned*)(ws + 21315600);  // 20 x 64-uint stride
    int*   counts = (int*)(ws + 21316880);         //   240,000
    int*   t2     = (int*)(ws + 21556880);         //        20

    // 1. prep + LN (1,503,760 items)
    prep_ln_kernel<<<5875, 256, 0, stream>>>(x, ln_g, ln_b, nxb, Wh, Wqk, Wout,
                                             rel_emb, WhT, Wqkb, WoutT, bias,
                                             hist, gmaxu);

    // 2. qk gemm + fused silu/rotary (M=10000, N=128, Kp=320):
    //    slice M over XCDs (157 m-tiles in 8 groups of 20), TX=2 n-tiles
    //    (4-wave kernel: only 314 tiles -> too few blocks for 1-wave version)
    gemm_nb<2><<<8 * 2 * 20, 256, 0, stream>>>(
        nxb, Wqkb, 320, 320, 320, 0L, 0L, 2, 20, 157,
        EpiQKRot{bqk, gamma, beta, qb, kb});

    // 3. gemm1 transposed -> vT bf16 + gateT fp32 (M=1200, N=10000, Kp=320):
    //    slice N over XCDs (157 n-tiles in 8 groups of 20), TY=19 m-tiles
    //    1-wave 64x64 kernel: 2983 tiles -> ~10 waves/CU, no staging dup
    gemm_nb1<1><<<8 * 20 * 19, 64, 0, stream>>>(
        WhT, nxb, 320, 320, 320, 0L, 0L, 20, 19, 157, EpiH{bh, vT, gateT});

    // 4. gate transpose -> gateNb bf16
    gate_transpose<<<dim3(19, 16, BB), 256, 0, stream>>>(gateT, gateNb);

    // 5-7. gate statistics (LDS-local hist, padded atomics)
    hist_accum_kernel<<<dim3(147, BB, 1), 256, 0, stream>>>(gateT, hist, gmaxu);
    counts_kernel<<<(BB * 100 * 120 + 255) / 256, 256, 0, stream>>>(gateT, hist, gmaxu, counts);
    t2_kernel<<<BB, 256, 0, stream>>>(counts, t2);

    // 8. scores -> attnb bf16 (per batch 500x500, Kp=128): batch b -> XCD b%8
    //    (4-wave kernel: K=128 too shallow / 1280 blocks too few for 1-wave)
    gemm_nb<0><<<8 * 8 * 8 * 3, 256, 0, stream>>>(
        qb, kb, QKD, QKD, QKD,
        (long)SS * QKD, (long)SS * QKD, 8, 8, BB, EpiAttnB{bias, mask2, attnb});

    // 9. attn@v + fused gate mask (per batch 500x640, Kp=512): batch b -> XCD b%8
    //    (same pin as scores -> attnb is read from the producing XCD's L2)
    //    1-wave 64x64 kernel: deep K=512 amortizes; 1600 tiles
    gemm_nb1<0><<<8 * 10 * 8 * 3, 64, 0, stream>>>(
        attnb, vT, 512, 512, 512,
        (long)SS * 512, (long)640 * 512, 10, 8, BB, EpiGateN{gateNb, counts, t2, gatedb});

    // 10. out = gated@Wout + bout + x (M=10000, N=300, Kp=608):
    //     slice M over XCDs, TX=5 n-tiles (4-wave kernel: 785 tiles)
    gemm_nb<2><<<8 * 5 * 20, 256, 0, stream>>>(
        gatedb, WoutT, 608, 608, 608, 0L, 0L, 5, 20, 157, EpiOutB{bout, x, out});
}

// Round 2
// 264.847 us; speedup vs baseline: 1.1260x; 1.1260x over previous
//
#include <hip/hip_runtime.h>
#include <hip/hip_bf16.h>

#define BB 20
#define SS 500
#define DIMD 300
#define HIDH 600
#define QKD 128

typedef unsigned short u16;
typedef __attribute__((ext_vector_type(8))) __bf16 bf16x8;
typedef __attribute__((ext_vector_type(8))) short short8;
typedef __attribute__((ext_vector_type(4))) float floatx4;

__device__ __forceinline__ u16 f2bu(float f) {
    __hip_bfloat16 h = __float2bfloat16(f);
    return *reinterpret_cast<u16*>(&h);
}
__device__ __forceinline__ float bu2f(u16 u) {
    unsigned v = ((unsigned)u) << 16;
    return __uint_as_float(v);
}

__device__ __forceinline__ floatx4 mfma_bf16(short8 a, short8 b, floatx4 c) {
    return __builtin_amdgcn_mfma_f32_16x16x32_bf16(
        __builtin_bit_cast(bf16x8, a), __builtin_bit_cast(bf16x8, b), c, 0, 0, 0);
}

// async global->LDS, 16B/lane; LDS dest = wave-uniform base + lane*16
__device__ __forceinline__ void glds16(const u16* g, u16* l) {
    __builtin_amdgcn_global_load_lds(
        (__attribute__((address_space(1))) const void*)g,
        (__attribute__((address_space(3))) void*)l, 16, 0, 0);
}

__device__ __forceinline__ unsigned fenc(float m) {
    unsigned bits = __float_as_uint(m);
    return (bits & 0x80000000u) ? ~bits : (bits | 0x80000000u);
}

// ---------------- merged prep + LayerNorm/shift ----------------
__global__ __launch_bounds__(256)
void prep_ln_kernel(const float* __restrict__ x, const float* __restrict__ lng,
                    const float* __restrict__ lnb, u16* __restrict__ nxb,
                    const float* __restrict__ Wh, const float* __restrict__ Wqk,
                    const float* __restrict__ Wout, const float* __restrict__ rel_emb,
                    u16* __restrict__ WhT, u16* __restrict__ Wqkb,
                    u16* __restrict__ WoutT, float* __restrict__ bias,
                    int* __restrict__ hist, unsigned* __restrict__ gmaxu) {
    long id = (long)blockIdx.x * 256 + threadIdx.x;
    if (id < 640000) {                        // LayerNorm + shift, one wave per row
        int bs = id >> 6;
        int t = id & 63;
        int s = bs % SS;
        const float* xr = x + (long)bs * DIMD;
        float sum = 0.f, sq = 0.f;
        for (int d = t; d < DIMD; d += 64) { float v = xr[d]; sum += v; sq += v * v; }
        for (int off = 1; off < 64; off <<= 1) {
            sum += __shfl_xor(sum, off);
            sq  += __shfl_xor(sq, off);
        }
        float mean = sum * (1.f / DIMD);
        float var  = sq * (1.f / DIMD) - mean * mean;
        float rstd = rsqrtf(var + 1e-5f);
        for (int d = t; d < DIMD; d += 64) {
            float nv = (xr[d] - mean) * rstd * lng[d] + lnb[d];
            if (d < DIMD / 2) {
                if (s < SS - 1) nxb[(long)(bs + 1) * 320 + d] = f2bu(nv);
            } else {
                nxb[(long)bs * 320 + d] = f2bu(nv);
            }
        }
        if (s == 0)
            for (int d = t; d < DIMD / 2; d += 64) nxb[(long)bs * 320 + d] = 0;
        for (int d = DIMD + t; d < 320; d += 64) nxb[(long)bs * 320 + d] = 0;
        return;
    }
    id -= 640000;
    if (id < 384000) {                        // WhT[n][k], k<320
        int k = id / 1200, n = id - (long)k * 1200;
        WhT[(long)n * 320 + k] = (k < 300) ? f2bu(Wh[(long)k * 1200 + n]) : (u16)0;
        return;
    }
    id -= 384000;
    if (id < 40960) {                         // Wqkb[n][k]
        int k = id / 128, n = id - (long)k * 128;
        Wqkb[(long)n * 320 + k] = (k < 300) ? f2bu(Wqk[(long)k * 128 + n]) : (u16)0;
        return;
    }
    id -= 40960;
    if (id < 182400) {                        // WoutT[n][k], k<608
        int k = id / 300, n = id - (long)k * 300;
        WoutT[(long)n * 608 + k] = (k < 600) ? f2bu(Wout[(long)k * 300 + n]) : (u16)0;
        return;
    }
    id -= 182400;
    if (id < 250000) {                        // T5 bias 500x500
        int i = id / 500, j = id - (long)i * 500;
        int n = i - j;
        int ret = (n < 0) ? 16 : 0;
        int na = n < 0 ? -n : n;
        int bucket;
        if (na < 8) bucket = ret + na;
        else {
            int vil = 8 + (int)(logf((float)na * 0.125f) / logf(16.f) * 8.f);
            vil = vil < 15 ? vil : 15;
            bucket = ret + vil;
        }
        bias[id] = rel_emb[bucket] * 11.313708498984761f;
        return;
    }
    id -= 250000;
    if (id < 5120) { hist[id] = 0; return; }   // 20 batches x 256-int stride
    id -= 5120;
    if (id < 1280) gmaxu[id] = 0u;             // 20 batches x 64-uint stride
}

// ---------------- Epilogues ----------------
// EpiH: gemm1 transposed (m = hidden [0,1200), n = token [0,10000)).
// Fuses the gate statistics that hist_accum_kernel used to compute by
// re-reading 24MB of gateT:
//   - hist: |g|>=1 is a ~4-sigma tail of silu(z) (z std ~0.35) -> a few
//     hundred events total; direct global atomicAdd is free.
//   - gmax: per-lane running max per 16-column slot (each lane owns 2 fixed
//     columns; slot = (n>>4)&1), then in finish() reduce over l4 (same
//     column), and across l15 when the 16-column group is batch-uniform
//     (one atomicMax/wave/slot).  Column groups are 16-aligned and
//     10000%16==0, so validity is wave-uniform per slot; the ~19 groups
//     straddling a 500-boundary fall back to per-column atomics (l4==0).
struct EpiH {
    const float* bh; u16* vT; float* gateT; int* hist; unsigned* gmaxu;
    float gm0 = -1e30f, gm1 = -1e30f;
    int nc0 = -1, nc1 = -1;
    __device__ void operator()(float acc, int bz, int m, int n) {
        if (m >= 1200 || n >= 10000) return;
        float v = acc + bh[m];
        v = v / (1.f + expf(-v));
        int b = n / SS, s = n - b * SS;
        if ((n >> 4) & 1) nc1 = n; else nc0 = n;   // column record (valid cols only)
        if (m < HIDH) { vT[((long)b * 640 + m) * 512 + s] = f2bu(v); return; }
        gateT[((long)b * HIDH + (m - HIDH)) * SS + s] = v;
        if ((n >> 4) & 1) gm1 = fmaxf(gm1, v); else gm0 = fmaxf(gm0, v);
        float ag = fabsf(v);
        if (ag >= 1.f) {
            int bin = (int)fminf(floorf(ag), 128.f);
            atomicAdd(&hist[b * 256 + bin], 1);
        }
    }
    __device__ void flush(float m, int nc) {
        if (nc < 0) return;                    // wave-uniform per slot (16-aligned)
        m = fmaxf(m, __shfl_xor(m, 16));       // reduce l4: same column
        m = fmaxf(m, __shfl_xor(m, 32));
        int base = nc & ~15;
        if (base / SS == (base + 15) / SS) {   // batch-uniform column group
            m = fmaxf(m, __shfl_xor(m, 1));
            m = fmaxf(m, __shfl_xor(m, 2));
            m = fmaxf(m, __shfl_xor(m, 4));
            m = fmaxf(m, __shfl_xor(m, 8));
            if ((threadIdx.x & 63) == 0 && m > -1e29f)
                atomicMax(&gmaxu[(base / SS) * 64], fenc(m));
        } else {                               // rare: group straddles batch edge
            if ((threadIdx.x & 63) < 16 && m > -1e29f)
                atomicMax(&gmaxu[(nc / SS) * 64], fenc(m));
        }
    }
    __device__ void finish() { flush(gm0, nc0); flush(gm1, nc1); }
};
struct EpiQKRot {        // qk + silu + gamma/beta + rotary (NO early return: shuffles)
    const float* bqk; const float* gamma; const float* beta;
    u16* qb; u16* kb;
    __device__ void operator()(float acc, int bz, int m, int n) const {
        float v = acc + bqk[n];
        v = v / (1.f + expf(-v));
        float qp = v * gamma[n] + beta[n];
        float kp = v * gamma[QKD + n] + beta[QKD + n];
        float qx = __shfl_xor(qp, 1);
        float kx = __shfl_xor(kp, 1);
        float qo = qp, ko = kp;
        if (n < 32) {
            int s = m % SS;
            float inv = expf(-(float)(n & ~1) * (logf(10000.f) / 32.f));
            float ang = (float)s * inv;
            float c, sn;
            sincosf(ang, &sn, &c);
            float qr = (n & 1) ? qx : -qx;
            float kr = (n & 1) ? kx : -kx;
            qo = qp * c + qr * sn;
            ko = kp * c + kr * sn;
        }
        if (m < 10000) {
            qb[(long)m * QKD + n] = f2bu(qo);
            kb[(long)m * QKD + n] = f2bu(ko);
        }
    }
    __device__ void finish() const {}
};
struct EpiAttnB {        // scores -> (relu((s+bias)/S))^2 * mask -> bf16 [500][512]
    const float* bias; const float* mask; u16* attnb;
    __device__ void operator()(float acc, int b, int m, int n) const {
        if (m >= SS || n >= 512) return;
        float r = 0.f;
        if (n < SS) {
            float s = (acc + bias[m * SS + n]) * (1.f / (float)SS);
            s = fmaxf(s, 0.f);
            r = s * s * mask[m * SS + n];
        }
        attnb[((long)b * SS + m) * 512 + n] = f2bu(r);
    }
    __device__ void finish() const {}
};
struct EpiGateN {        // gated = gm * (attn@v) * gate -> bf16 [10000][608]
    // reads gateT fp32 directly (batch slice is 1.2MB, L2-resident on the
    // XCD this batch is pinned to) -> gate_transpose/gateNb eliminated, and
    // the gate multiply is fp32 (closer to reference than the bf16 round-trip)
    const float* gateT; const int* counts; const int* t2v; u16* gated;
    __device__ void operator()(float acc, int b, int m, int n) const {
        if (m >= SS || n >= 608) return;
        float r = 0.f;
        if (n < HIDH) {
            float g = gateT[((long)b * HIDH + n) * SS + m];
            int c = counts[(b * 100 + m / 5) * 120 + n / 5];
            float bv = (c >= t2v[b]) ? 1.f : 0.25f;
            float p = ((m % 5) == 4 || (n % 5) == 4) ? 0.f : 1.f;
            r = acc * g * bv * p;
        }
        gated[((long)(b * SS + m)) * 608 + n] = f2bu(r);
    }
    __device__ void finish() const {}
};
struct EpiOutB {         // out = gated@Wout + bout + x
    const float* bout; const float* x; float* out;
    __device__ void operator()(float acc, int b, int m, int n) const {
        if (m >= 10000 || n >= DIMD) return;
        out[(long)m * DIMD + n] = acc + bout[n] + x[(long)m * DIMD + n];
    }
    __device__ void finish() const {}
};

// ---------------- barrier-free bf16 MFMA GEMM: per-wave LDS dbuf + XCD pinning ----------------
// C[M,N] = A[M,Kp] * Bt[N,Kp]^T.  Block 64x64 = 4 waves in 2x2; each wave owns
// a 32x32 tile with its OWN private LDS double-buffer.  No __syncthreads
// -> no compiler vmcnt(0) drain; explicit per-wave s_waitcnt vmcnt(4) retires
// only the current buffer's 4 glds while the prefetch stays in flight
// (retirement is issue-ordered, m135).  32KB LDS/block.  (R1 lesson: the
// 1-wave 64x64 variant halves traffic but drops occupancy 32->15% and loses
// 20% -- resident-wave latency cover is the binding constraint, not traffic.)
// 1-D grid with XCD pinning (workgroup->XCD is round-robin on linear id).
// MODE 0: batch g -> XCD g%8.  MODE 1: slice N into per-XCD groups of TX
// n-tiles.  MODE 2: slice M into groups of TY m-tiles.
// Early whole-block return is safe (no barriers).  Staging has NO bounds
// checks: overruns read adjacent ws buffers (finite garbage discarded by
// epilogue guards); K-pads are real zeros in memory.
template<int MODE, class Epi>
__global__ __launch_bounds__(256)
void gemm_nb(const u16* __restrict__ A, const u16* __restrict__ Bt,
             int Kp, int lda, int ldb, long sA, long sB,
             int TX, int TY, int bound, Epi epi) {
    int lin = blockIdx.x;
    int xcd = lin & 7, i = lin >> 3;
    int per = TX * TY;
    int w = i / per;
    int tl = i - w * per;
    int g = xcd + (w << 3);
    int tx = tl % TX, ty = tl / TX;
    int bx, by, bz;
    if (MODE == 0)      { if (g >= bound) return; bx = tx; by = ty; bz = g; }
    else if (MODE == 1) { bx = g * TX + tx; if (bx >= bound) return; by = ty; bz = 0; }
    else                { by = g * TY + ty; if (by >= bound) return; bx = tx; bz = 0; }

    A += (long)bz * sA; Bt += (long)bz * sB;
    int t = threadIdx.x, lane = t & 63, wave = t >> 6;
    int l15 = lane & 15, l4 = lane >> 4;
    int m0 = (by << 6) + ((wave >> 1) << 5);
    int n0 = (bx << 6) + ((wave & 1) << 5);

    // [wave][buf][row 0..31=A,32..63=B][k32] ; unpadded 64B rows (glds contract)
    __shared__ __align__(16) u16 S[4][2][64][32];

    int srow = lane >> 2, scol = (lane & 3) << 3;
    const u16* agp0 = A + (long)(m0 + srow) * lda + scol;
    const u16* agp1 = A + (long)(m0 + 16 + srow) * lda + scol;
    const u16* bgp0 = Bt + (long)(n0 + srow) * ldb + scol;
    const u16* bgp1 = Bt + (long)(n0 + 16 + srow) * ldb + scol;

    floatx4 acc[2][2];
#pragma unroll
    for (int i2 = 0; i2 < 2; ++i2)
#pragma unroll
        for (int j = 0; j < 2; ++j) acc[i2][j] = (floatx4){0.f, 0.f, 0.f, 0.f};

    // prologue stage into buf 0 (4 outstanding)
    glds16(agp0, &S[wave][0][0][0]);
    glds16(agp1, &S[wave][0][16][0]);
    glds16(bgp0, &S[wave][0][32][0]);
    glds16(bgp1, &S[wave][0][48][0]);

    for (int k0 = 0; k0 < Kp; k0 += 32) {
        int buf = (k0 >> 5) & 1;
        int kn = k0 + 32;
        if (kn < Kp) {                       // prefetch next into back buffer
            int nb = buf ^ 1;
            glds16(agp0 + kn, &S[wave][nb][0][0]);
            glds16(agp1 + kn, &S[wave][nb][16][0]);
            glds16(bgp0 + kn, &S[wave][nb][32][0]);
            glds16(bgp1 + kn, &S[wave][nb][48][0]);
            // wait ONLY for current buf's 4 loads; prefetch stays in flight
            asm volatile("s_waitcnt vmcnt(4)" ::: "memory");
        } else {
            asm volatile("s_waitcnt vmcnt(0)" ::: "memory");
        }
        short8 a0 = *(const short8*)(&S[wave][buf][l15][l4 << 3]);
        short8 a1 = *(const short8*)(&S[wave][buf][16 + l15][l4 << 3]);
        short8 b0 = *(const short8*)(&S[wave][buf][32 + l15][l4 << 3]);
        short8 b1 = *(const short8*)(&S[wave][buf][48 + l15][l4 << 3]);
        acc[0][0] = mfma_bf16(a0, b0, acc[0][0]);
        acc[0][1] = mfma_bf16(a0, b1, acc[0][1]);
        acc[1][0] = mfma_bf16(a1, b0, acc[1][0]);
        acc[1][1] = mfma_bf16(a1, b1, acc[1][1]);
    }
#pragma unroll
    for (int i2 = 0; i2 < 2; ++i2) {
        int bm = m0 + (i2 << 4) + (l4 << 2);
#pragma unroll
        for (int j = 0; j < 2; ++j) {
            int bn = n0 + (j << 4) + l15;
#pragma unroll
            for (int r = 0; r < 4; ++r)
                epi(acc[i2][j][r], bz, bm + r, bn);
        }
    }
    epi.finish();
}

// counts over gateT[h][s] with integrated per-thread trim
__global__ void counts_kernel(const float* __restrict__ gateT, const int* __restrict__ hist,
                              const unsigned* __restrict__ gmaxu, int* __restrict__ counts) {
    int id = blockIdx.x * 256 + threadIdx.x;
    if (id >= BB * 100 * 120) return;
    int b = id / 12000;
    unsigned enc = gmaxu[b * 64];
    unsigned bits = (enc & 0x80000000u) ? (enc & 0x7FFFFFFFu) : ~enc;
    float gmax = floorf(__uint_as_float(bits));
    int suffix = 0, trim = 1;
    for (int tt = 128; tt >= 1; --tt) {
        suffix += hist[b * 256 + tt];
        if ((float)tt <= gmax && suffix > 90000) { trim = tt; break; }
    }
    float tr = (float)trim;
    int r = id - b * 12000;
    int bi = r / 120, bj = r - bi * 120;
    const float* gb = gateT + (long)b * SS * HIDH;
    int c = 0;
#pragma unroll
    for (int cc = 0; cc < 4; ++cc)
#pragma unroll
        for (int rr = 0; rr < 4; ++rr) {
            float g = gb[(long)(bj * 5 + cc) * SS + bi * 5 + rr];
            c += (fabsf(g) >= tr) ? 1 : 0;
        }
    counts[id] = c;
}

__global__ __launch_bounds__(256)
void t2_kernel(const int* __restrict__ counts, int* __restrict__ t2) {
    int b = blockIdx.x;
    int t = threadIdx.x;
    __shared__ int h2[17];
    __shared__ int smax;
    if (t < 17) h2[t] = 0;
    if (t == 0) smax = 0;
    __syncthreads();
    int lmax = 0;
    for (int i = t; i < 12000; i += 256) {
        int c = counts[b * 12000 + i];
        if (c) atomicAdd(&h2[c], 1);
        lmax = lmax > c ? lmax : c;
    }
    atomicMax(&smax, lmax);
    __syncthreads();
    if (t == 0) {
        int cmax = smax;
        int suffix = 0, best = 0;
        bool found = false;
        for (int tt = 16; tt >= 1; --tt) {
            suffix += h2[tt];
            if (!found && tt <= cmax && suffix > 3600) { best = tt; found = true; }
        }
        t2[b] = found ? best : cmax;
    }
}

extern "C" void kernel_launch(void* const* d_in, const int* in_sizes, int n_in,
                              void* d_out, int out_size, void* d_ws, size_t ws_size,
                              hipStream_t stream) {
    const float* x      = (const float*)d_in[0];
    const float* mask2  = (const float*)d_in[1];
    const float* ln_g   = (const float*)d_in[2];
    const float* ln_b   = (const float*)d_in[3];
    const float* Wh     = (const float*)d_in[4];
    const float* bh     = (const float*)d_in[5];
    const float* Wqk    = (const float*)d_in[6];
    const float* bqk    = (const float*)d_in[7];
    const float* gamma  = (const float*)d_in[8];
    const float* beta   = (const float*)d_in[9];
    const float* rel_emb= (const float*)d_in[10];
    const float* Wout   = (const float*)d_in[11];
    const float* bout   = (const float*)d_in[12];
    float* out = (float*)d_out;
    float* ws  = (float*)d_ws;

    // workspace layout (float offsets; all 16B-aligned)
    float* gateT  = ws;                            //  6,000,000 f
    float* bias   = ws + 6000000;                  //    250,000 f
    u16*   nxb    = (u16*)(ws + 6250000);          // 10000x320 u16
    u16*   WhT    = (u16*)(ws + 7850000);          //  1200x320 u16
    u16*   Wqkb   = (u16*)(ws + 8042000);          //   128x320 u16
    u16*   WoutT  = (u16*)(ws + 8062480);          //   300x608 u16
    u16*   qb     = (u16*)(ws + 8153680);          // 10000x128 u16
    u16*   kb     = (u16*)(ws + 8793680);          // 10000x128 u16
    u16*   attnb  = (u16*)(ws + 9433680);          // 20x500x512 u16
    u16*   vT     = (u16*)(ws + 11993680);         // 20x640x512 u16
    u16*   gatedb = (u16*)(ws + 15270480);         // 10000x608 u16
    int*   hist   = (int*)(ws + 21310480);         // 20 x 256-int stride
    unsigned* gmaxu = (unsigned*)(ws + 21315600);  // 20 x 64-uint stride
    int*   counts = (int*)(ws + 21316880);         //   240,000
    int*   t2     = (int*)(ws + 21556880);         //        20

    // 1. prep + LN (1,503,760 items); also zeroes hist/gmaxu for step 3
    prep_ln_kernel<<<5875, 256, 0, stream>>>(x, ln_g, ln_b, nxb, Wh, Wqk, Wout,
                                             rel_emb, WhT, Wqkb, WoutT, bias,
                                             hist, gmaxu);

    // 2. qk gemm + fused silu/rotary (M=10000, N=128, Kp=320):
    //    slice M over XCDs (157 m-tiles in 8 groups of 20), TX=2 n-tiles
    gemm_nb<2><<<8 * 2 * 20, 256, 0, stream>>>(
        nxb, Wqkb, 320, 320, 320, 0L, 0L, 2, 20, 157,
        EpiQKRot{bqk, gamma, beta, qb, kb});

    // 3. gemm1 transposed -> vT bf16 + gateT fp32 + FUSED hist/gmax
    //    (M=1200, N=10000, Kp=320): slice N over XCDs, TY=19 m-tiles
    gemm_nb<1><<<8 * 20 * 19, 256, 0, stream>>>(
        WhT, nxb, 320, 320, 320, 0L, 0L, 20, 19, 157,
        EpiH{bh, vT, gateT, hist, gmaxu});

    // 4-5. gate statistics (hist/gmax already produced by step 3's epilogue)
    counts_kernel<<<(BB * 100 * 120 + 255) / 256, 256, 0, stream>>>(gateT, hist, gmaxu, counts);
    t2_kernel<<<BB, 256, 0, stream>>>(counts, t2);

    // 6. scores -> attnb bf16 (per batch 500x500, Kp=128): batch b -> XCD b%8
    gemm_nb<0><<<8 * 8 * 8 * 3, 256, 0, stream>>>(
        qb, kb, QKD, QKD, QKD,
        (long)SS * QKD, (long)SS * QKD, 8, 8, BB, EpiAttnB{bias, mask2, attnb});

    // 7. attn@v + fused gate mask (per batch 500x640, Kp=512): batch b -> XCD b%8
    //    (same pin as scores -> attnb + gateT[b] read from this XCD's L2)
    gemm_nb<0><<<8 * 10 * 8 * 3, 256, 0, stream>>>(
        attnb, vT, 512, 512, 512,
        (long)SS * 512, (long)640 * 512, 10, 8, BB,
        EpiGateN{gateT, counts, t2, gatedb});

    // 8. out = gated@Wout + bout + x (M=10000, N=300, Kp=608):
    //    slice M over XCDs, TX=5 n-tiles
    gemm_nb<2><<<8 * 5 * 20, 256, 0, stream>>>(
        gatedb, WoutT, 608, 608, 608, 0L, 0L, 5, 20, 157, EpiOutB{bout, x, out});
}

// Round 3
// 229.216 us; speedup vs baseline: 1.3011x; 1.1554x over previous
//
#include <hip/hip_runtime.h>
#include <hip/hip_bf16.h>

#define BB 20
#define SS 500
#define DIMD 300
#define HIDH 600
#define QKD 128

typedef unsigned short u16;
typedef __attribute__((ext_vector_type(8))) __bf16 bf16x8;
typedef __attribute__((ext_vector_type(8))) short short8;
typedef __attribute__((ext_vector_type(4))) float floatx4;

__device__ __forceinline__ u16 f2bu(float f) {
    __hip_bfloat16 h = __float2bfloat16(f);
    return *reinterpret_cast<u16*>(&h);
}
__device__ __forceinline__ float bu2f(u16 u) {
    unsigned v = ((unsigned)u) << 16;
    return __uint_as_float(v);
}

__device__ __forceinline__ floatx4 mfma_bf16(short8 a, short8 b, floatx4 c) {
    return __builtin_amdgcn_mfma_f32_16x16x32_bf16(
        __builtin_bit_cast(bf16x8, a), __builtin_bit_cast(bf16x8, b), c, 0, 0, 0);
}

// async global->LDS, 16B/lane; LDS dest = wave-uniform base + lane*16
__device__ __forceinline__ void glds16(const u16* g, u16* l) {
    __builtin_amdgcn_global_load_lds(
        (__attribute__((address_space(1))) const void*)g,
        (__attribute__((address_space(3))) void*)l, 16, 0, 0);
}

__device__ __forceinline__ unsigned fenc(float m) {
    unsigned bits = __float_as_uint(m);
    return (bits & 0x80000000u) ? ~bits : (bits | 0x80000000u);
}

// ---------------- merged prep + LayerNorm/shift ----------------
__global__ __launch_bounds__(256)
void prep_ln_kernel(const float* __restrict__ x, const float* __restrict__ lng,
                    const float* __restrict__ lnb, u16* __restrict__ nxb,
                    const float* __restrict__ Wh, const float* __restrict__ Wqk,
                    const float* __restrict__ Wout, const float* __restrict__ rel_emb,
                    u16* __restrict__ WhT, u16* __restrict__ Wqkb,
                    u16* __restrict__ WoutT, float* __restrict__ bias,
                    int* __restrict__ hist, unsigned* __restrict__ gmaxu,
                    int* __restrict__ h2cm) {
    long id = (long)blockIdx.x * 256 + threadIdx.x;
    if (id < 640000) {                        // LayerNorm + shift, one wave per row
        int bs = id >> 6;
        int t = id & 63;
        int s = bs % SS;
        const float* xr = x + (long)bs * DIMD;
        float sum = 0.f, sq = 0.f;
        for (int d = t; d < DIMD; d += 64) { float v = xr[d]; sum += v; sq += v * v; }
        for (int off = 1; off < 64; off <<= 1) {
            sum += __shfl_xor(sum, off);
            sq  += __shfl_xor(sq, off);
        }
        float mean = sum * (1.f / DIMD);
        float var  = sq * (1.f / DIMD) - mean * mean;
        float rstd = rsqrtf(var + 1e-5f);
        for (int d = t; d < DIMD; d += 64) {
            float nv = (xr[d] - mean) * rstd * lng[d] + lnb[d];
            if (d < DIMD / 2) {
                if (s < SS - 1) nxb[(long)(bs + 1) * 320 + d] = f2bu(nv);
            } else {
                nxb[(long)bs * 320 + d] = f2bu(nv);
            }
        }
        if (s == 0)
            for (int d = t; d < DIMD / 2; d += 64) nxb[(long)bs * 320 + d] = 0;
        for (int d = DIMD + t; d < 320; d += 64) nxb[(long)bs * 320 + d] = 0;
        return;
    }
    id -= 640000;
    if (id < 384000) {                        // WhT[n][k], k<320
        int k = id / 1200, n = id - (long)k * 1200;
        WhT[(long)n * 320 + k] = (k < 300) ? f2bu(Wh[(long)k * 1200 + n]) : (u16)0;
        return;
    }
    id -= 384000;
    if (id < 40960) {                         // Wqkb[n][k]
        int k = id / 128, n = id - (long)k * 128;
        Wqkb[(long)n * 320 + k] = (k < 300) ? f2bu(Wqk[(long)k * 128 + n]) : (u16)0;
        return;
    }
    id -= 40960;
    if (id < 182400) {                        // WoutT[n][k], k<608
        int k = id / 300, n = id - (long)k * 300;
        WoutT[(long)n * 608 + k] = (k < 600) ? f2bu(Wout[(long)k * 300 + n]) : (u16)0;
        return;
    }
    id -= 182400;
    if (id < 250000) {                        // T5 bias 500x500
        int i = id / 500, j = id - (long)i * 500;
        int n = i - j;
        int ret = (n < 0) ? 16 : 0;
        int na = n < 0 ? -n : n;
        int bucket;
        if (na < 8) bucket = ret + na;
        else {
            int vil = 8 + (int)(logf((float)na * 0.125f) / logf(16.f) * 8.f);
            vil = vil < 15 ? vil : 15;
            bucket = ret + vil;
        }
        bias[id] = rel_emb[bucket] * 11.313708498984761f;
        return;
    }
    id -= 250000;
    if (id < 5120) { hist[id] = 0; return; }   // 20 batches x 256-int stride
    id -= 5120;
    if (id < 1280) { gmaxu[id] = 0u; return; } // 20 batches x 64-uint stride
    id -= 1280;
    if (id < 1280) h2cm[(int)id] = 0;          // h2 hist (20x32) + cmax (20x32)
}

// ---------------- Epilogues ----------------
// All epilogues implement: init(bz) pre-K-loop hook, operator()(acc,bz,m,n,j)
// with j = compile-time n-subtile slot (0/1), finish(bz,m0,n0) post hook.

// EpiH: gemm1 transposed (m = hidden [0,1200), n = token [0,10000)).
// Fuses gate stats (saves re-reading 24MB of gateT):
//   - hist: |g|>=1 is a ~4-sigma tail -> a few hundred atomics total.
//   - gmax: per-lane running max per n-slot.  R2 lesson: per-call column
//     TRACKING (nc0/nc1) serialized the 16 unrolled epilogue calls and cost
//     ~6us idle; columns are STATIC per wave (slot j covers n0+16j+l15), so
//     slot selection now folds at compile time and finish() derives columns
//     from n0.  Column groups are 16-aligned, 10000%16==0 -> group validity
//     and (usually) batch are wave-uniform; straddling groups (500%16!=0)
//     fall back to per-column atomics from lanes 0..15.
struct EpiH {
    const float* bh; u16* vT; float* gateT; int* hist; unsigned* gmaxu;
    float gm0 = -1e30f, gm1 = -1e30f;
    __device__ void init(int) {}
    __device__ void operator()(float acc, int bz, int m, int n, int j) {
        if (m >= 1200 || n >= 10000) return;
        float v = acc + bh[m];
        v = v / (1.f + expf(-v));
        int b = n / SS, s = n - b * SS;
        if (m < HIDH) { vT[((long)b * 640 + m) * 512 + s] = f2bu(v); return; }
        gateT[((long)b * HIDH + (m - HIDH)) * SS + s] = v;
        if (j) gm1 = fmaxf(gm1, v); else gm0 = fmaxf(gm0, v);
        float ag = fabsf(v);
        if (ag >= 1.f) {
            int bin = (int)fminf(floorf(ag), 128.f);
            atomicAdd(&hist[b * 256 + bin], 1);
        }
    }
    __device__ void flushS(float m, int base) {
        if (base >= 10000) return;
        m = fmaxf(m, __shfl_xor(m, 16));       // reduce over l4 (same column)
        m = fmaxf(m, __shfl_xor(m, 32));
        int b0 = base / SS;
        if (b0 == (base + 15) / SS) {          // batch-uniform column group
            m = fmaxf(m, __shfl_xor(m, 1));
            m = fmaxf(m, __shfl_xor(m, 2));
            m = fmaxf(m, __shfl_xor(m, 4));
            m = fmaxf(m, __shfl_xor(m, 8));
            if ((threadIdx.x & 63) == 0 && m > -1e29f)
                atomicMax(&gmaxu[b0 * 64], fenc(m));
        } else {                               // group straddles batch edge
            int l = threadIdx.x & 63;
            if (l < 16 && m > -1e29f)
                atomicMax(&gmaxu[((base + l) / SS) * 64], fenc(m));
        }
    }
    __device__ void finish(int bz, int m0, int n0) {
        if (m0 + 32 <= 600) return;            // wave has no gate rows
        flushS(gm0, n0);
        flushS(gm1, n0 + 16);
    }
};
struct EpiQKRot {        // qk + silu + gamma/beta + rotary (NO early return: shuffles)
    const float* bqk; const float* gamma; const float* beta;
    u16* qb; u16* kb;
    __device__ void init(int) const {}
    __device__ void operator()(float acc, int bz, int m, int n, int j) const {
        float v = acc + bqk[n];
        v = v / (1.f + expf(-v));
        float qp = v * gamma[n] + beta[n];
        float kp = v * gamma[QKD + n] + beta[QKD + n];
        float qx = __shfl_xor(qp, 1);
        float kx = __shfl_xor(kp, 1);
        float qo = qp, ko = kp;
        if (n < 32) {
            int s = m % SS;
            float inv = expf(-(float)(n & ~1) * (logf(10000.f) / 32.f));
            float ang = (float)s * inv;
            float c, sn;
            sincosf(ang, &sn, &c);
            float qr = (n & 1) ? qx : -qx;
            float kr = (n & 1) ? kx : -kx;
            qo = qp * c + qr * sn;
            ko = kp * c + kr * sn;
        }
        if (m < 10000) {
            qb[(long)m * QKD + n] = f2bu(qo);
            kb[(long)m * QKD + n] = f2bu(ko);
        }
    }
    __device__ void finish(int, int, int) const {}
};
struct EpiAttnB {        // scores -> (relu((s+bias)/S))^2 * mask -> bf16 [500][512]
    const float* bias; const float* mask; u16* attnb;
    __device__ void init(int) const {}
    __device__ void operator()(float acc, int b, int m, int n, int j) const {
        if (m >= SS || n >= 512) return;
        float r = 0.f;
        if (n < SS) {
            float s = (acc + bias[m * SS + n]) * (1.f / (float)SS);
            s = fmaxf(s, 0.f);
            r = s * s * mask[m * SS + n];
        }
        attnb[((long)b * SS + m) * 512 + n] = f2bu(r);
    }
    __device__ void finish(int, int, int) const {}
};
struct EpiGateN {        // gated = gm * (attn@v) * gate -> bf16 [10000][608]
    // reads gateT fp32 directly (batch slice is 1.2MB, L2-resident on the
    // XCD this batch is pinned to).  t2[b] computed per-thread in init()
    // from the global h2-hist/cmax that counts blocks accumulated ->
    // t2_kernel launch eliminated.  17 uniform L2 loads, hidden under the
    // staging prologue.
    const float* gateT; const int* counts; const int* h2cm; u16* gated;
    int t2 = 0;
    __device__ void init(int b) {
        int cmax = h2cm[640 + b * 32];
        int suffix = 0, best = 0;
        bool found = false;
        for (int tt = 16; tt >= 1; --tt) {
            suffix += h2cm[b * 32 + tt];
            if (!found && tt <= cmax && suffix > 3600) { best = tt; found = true; }
        }
        t2 = found ? best : cmax;
    }
    __device__ void operator()(float acc, int b, int m, int n, int j) const {
        if (m >= SS || n >= 608) return;
        float r = 0.f;
        if (n < HIDH) {
            float g = gateT[((long)b * HIDH + n) * SS + m];
            int c = counts[(b * 100 + m / 5) * 120 + n / 5];
            float bv = (c >= t2) ? 1.f : 0.25f;
            float p = ((m % 5) == 4 || (n % 5) == 4) ? 0.f : 1.f;
            r = acc * g * bv * p;
        }
        gated[((long)(b * SS + m)) * 608 + n] = f2bu(r);
    }
    __device__ void finish(int, int, int) const {}
};
struct EpiOutB {         // out = gated@Wout + bout + x
    const float* bout; const float* x; float* out;
    __device__ void init(int) const {}
    __device__ void operator()(float acc, int b, int m, int n, int j) const {
        if (m >= 10000 || n >= DIMD) return;
        out[(long)m * DIMD + n] = acc + bout[n] + x[(long)m * DIMD + n];
    }
    __device__ void finish(int, int, int) const {}
};

// ---------------- barrier-free bf16 MFMA GEMM body ----------------
// C[M,N] = A[M,Kp] * Bt[N,Kp]^T.  Block 64x64 = 4 waves in 2x2; each wave owns
// a 32x32 tile with its OWN private LDS double-buffer (8KB/wave, 32KB/block).
// No __syncthreads -> no compiler vmcnt(0) drain; explicit per-wave s_waitcnt
// vmcnt(4) retires only the current buffer's 4 glds while the prefetch stays
// in flight (retirement is issue-ordered, m135).  (R1 lesson: 1-wave 64x64
// halves traffic but drops occupancy 32->15% and loses 20% -- resident-wave
// latency cover is the binding constraint, not traffic.)
// 1-D grid with XCD pinning (workgroup->XCD is round-robin on linear id).
// MODE 0: batch g -> XCD g%8.  MODE 1: slice N into per-XCD groups of TX
// n-tiles.  MODE 2: slice M into groups of TY m-tiles.
// Factored as a __device__ body (LDS passed in) so independent latency-bound
// GEMMs can be fused into one launch and overlap (all pipes <40% busy).
// Early whole-block return is safe (no barriers).  Staging has NO bounds
// checks: overruns read adjacent ws buffers (finite garbage discarded by
// epilogue guards); K-pads are real zeros in memory.
template<int MODE, class Epi>
__device__ __forceinline__ void gemm_body(
        int lin, u16* __restrict__ S,
        const u16* __restrict__ A, const u16* __restrict__ Bt,
        int Kp, int lda, int ldb, long sA, long sB,
        int TX, int TY, int bound, Epi epi) {
    int xcd = lin & 7, i = lin >> 3;
    int per = TX * TY;
    int w = i / per;
    int tl = i - w * per;
    int g = xcd + (w << 3);
    int tx = tl % TX, ty = tl / TX;
    int bx, by, bz;
    if (MODE == 0)      { if (g >= bound) return; bx = tx; by = ty; bz = g; }
    else if (MODE == 1) { bx = g * TX + tx; if (bx >= bound) return; by = ty; bz = 0; }
    else                { by = g * TY + ty; if (by >= bound) return; bx = tx; bz = 0; }

    A += (long)bz * sA; Bt += (long)bz * sB;
    int t = threadIdx.x, lane = t & 63, wave = t >> 6;
    int l15 = lane & 15, l4 = lane >> 4;
    int m0 = (by << 6) + ((wave >> 1) << 5);
    int n0 = (bx << 6) + ((wave & 1) << 5);

    epi.init(bz);

    // per-wave LDS: [buf][row 0..31=A,32..63=B][k32], 4096 u16
    u16* SW = S + (wave << 12);

    int srow = lane >> 2, scol = (lane & 3) << 3;
    const u16* agp0 = A + (long)(m0 + srow) * lda + scol;
    const u16* agp1 = A + (long)(m0 + 16 + srow) * lda + scol;
    const u16* bgp0 = Bt + (long)(n0 + srow) * ldb + scol;
    const u16* bgp1 = Bt + (long)(n0 + 16 + srow) * ldb + scol;

    floatx4 acc[2][2];
#pragma unroll
    for (int i2 = 0; i2 < 2; ++i2)
#pragma unroll
        for (int j = 0; j < 2; ++j) acc[i2][j] = (floatx4){0.f, 0.f, 0.f, 0.f};

    // prologue stage into buf 0 (4 outstanding)
    glds16(agp0, SW + 0 * 32);
    glds16(agp1, SW + 16 * 32);
    glds16(bgp0, SW + 32 * 32);
    glds16(bgp1, SW + 48 * 32);

    for (int k0 = 0; k0 < Kp; k0 += 32) {
        int buf = (k0 >> 5) & 1;
        u16* SB = SW + (buf << 11);
        int kn = k0 + 32;
        if (kn < Kp) {                       // prefetch next into back buffer
            u16* SN = SW + ((buf ^ 1) << 11);
            glds16(agp0 + kn, SN + 0 * 32);
            glds16(agp1 + kn, SN + 16 * 32);
            glds16(bgp0 + kn, SN + 32 * 32);
            glds16(bgp1 + kn, SN + 48 * 32);
            // wait ONLY for current buf's 4 loads; prefetch stays in flight
            asm volatile("s_waitcnt vmcnt(4)" ::: "memory");
        } else {
            asm volatile("s_waitcnt vmcnt(0)" ::: "memory");
        }
        short8 a0 = *(const short8*)(SB + l15 * 32 + (l4 << 3));
        short8 a1 = *(const short8*)(SB + (16 + l15) * 32 + (l4 << 3));
        short8 b0 = *(const short8*)(SB + (32 + l15) * 32 + (l4 << 3));
        short8 b1 = *(const short8*)(SB + (48 + l15) * 32 + (l4 << 3));
        acc[0][0] = mfma_bf16(a0, b0, acc[0][0]);
        acc[0][1] = mfma_bf16(a0, b1, acc[0][1]);
        acc[1][0] = mfma_bf16(a1, b0, acc[1][0]);
        acc[1][1] = mfma_bf16(a1, b1, acc[1][1]);
    }
#pragma unroll
    for (int i2 = 0; i2 < 2; ++i2) {
        int bm = m0 + (i2 << 4) + (l4 << 2);
#pragma unroll
        for (int j = 0; j < 2; ++j) {
            int bn = n0 + (j << 4) + l15;
#pragma unroll
            for (int r = 0; r < 4; ++r)
                epi(acc[i2][j][r], bz, bm + r, bn, j);
        }
    }
    epi.finish(bz, m0, n0);
}

// standalone wrapper (static LDS)
template<int MODE, class Epi>
__global__ __launch_bounds__(256)
void gemm_nb(const u16* __restrict__ A, const u16* __restrict__ Bt,
             int Kp, int lda, int ldb, long sA, long sB,
             int TX, int TY, int bound, Epi epi) {
    __shared__ __align__(16) u16 S[4 * 4096];
    gemm_body<MODE>(blockIdx.x, S, A, Bt, Kp, lda, ldb, sA, sB, TX, TY, bound, epi);
}

// merged qk-gemm (blocks [0,320)) + h-gemm (blocks [320,3360)).  Independent,
// both read nxb, both latency-bound (<40% on all pipes) -> overlap in one
// launch.  Offset 320%8==0 preserves the h-gemm's XCD slicing.  Dynamic LDS
// (32KB) so the two inlined bodies share one allocation.
__global__ __launch_bounds__(256)
void gemm_qk_h(const u16* __restrict__ nxb, const u16* __restrict__ Wqkb,
               const u16* __restrict__ WhT, EpiQKRot eq, EpiH eh) {
    extern __shared__ u16 S[];
    int lin = blockIdx.x;
    if (lin < 320)
        gemm_body<2>(lin, S, nxb, Wqkb, 320, 320, 320, 0L, 0L, 2, 20, 157, eq);
    else
        gemm_body<1>(lin - 320, S, WhT, nxb, 320, 320, 320, 0L, 0L, 20, 19, 157, eh);
}

// merged scores-gemm (blocks [0,1536)) + counts (blocks [1536,2476)).
// counts: 47 blocks per batch; per-block LDS h2-hist + max, one global
// atomicAdd per bin per block into h2cm (hist 20x32 @0, cmax 20x32 @640).
__global__ __launch_bounds__(256)
void gemm_sc(const u16* __restrict__ qb, const u16* __restrict__ kb, EpiAttnB ea,
             const float* __restrict__ gateT, const int* __restrict__ hist,
             const unsigned* __restrict__ gmaxu, int* __restrict__ counts,
             int* __restrict__ h2cm) {
    extern __shared__ u16 S[];
    int lin = blockIdx.x;
    if (lin < 1536) {
        gemm_body<0>(lin, S, qb, kb, QKD, QKD, QKD,
                     (long)SS * QKD, (long)SS * QKD, 8, 8, BB, ea);
        return;
    }
    int cb = lin - 1536;
    int b = cb / 47, blk = cb - b * 47;
    int r = blk * 256 + threadIdx.x;
    int* h2l = (int*)S;
    int* smaxp = h2l + 17;
    if (threadIdx.x < 17) h2l[threadIdx.x] = 0;
    if (threadIdx.x == 0) *smaxp = 0;
    __syncthreads();
    int c = 0;
    if (r < 12000) {
        unsigned enc = gmaxu[b * 64];
        unsigned bits = (enc & 0x80000000u) ? (enc & 0x7FFFFFFFu) : ~enc;
        float gmax = floorf(__uint_as_float(bits));
        int suffix = 0, trim = 1;
        for (int tt = 128; tt >= 1; --tt) {
            suffix += hist[b * 256 + tt];
            if ((float)tt <= gmax && suffix > 90000) { trim = tt; break; }
        }
        float tr = (float)trim;
        int bi = r / 120, bj = r - bi * 120;
        const float* gb = gateT + (long)b * SS * HIDH;
#pragma unroll
        for (int cc = 0; cc < 4; ++cc)
#pragma unroll
            for (int rr = 0; rr < 4; ++rr) {
                float gv = gb[(long)(bj * 5 + cc) * SS + bi * 5 + rr];
                c += (fabsf(gv) >= tr) ? 1 : 0;
            }
        counts[b * 12000 + r] = c;
        if (c) atomicAdd(&h2l[c], 1);
    }
    int lmax = c;
    for (int off = 32; off; off >>= 1) {
        int o = __shfl_xor(lmax, off);
        lmax = lmax > o ? lmax : o;
    }
    if ((threadIdx.x & 63) == 0) atomicMax(smaxp, lmax);
    __syncthreads();
    if (threadIdx.x < 17 && h2l[threadIdx.x])
        atomicAdd(&h2cm[b * 32 + threadIdx.x], h2l[threadIdx.x]);
    if (threadIdx.x == 0) atomicMax(&h2cm[640 + b * 32], *smaxp);
}

extern "C" void kernel_launch(void* const* d_in, const int* in_sizes, int n_in,
                              void* d_out, int out_size, void* d_ws, size_t ws_size,
                              hipStream_t stream) {
    const float* x      = (const float*)d_in[0];
    const float* mask2  = (const float*)d_in[1];
    const float* ln_g   = (const float*)d_in[2];
    const float* ln_b   = (const float*)d_in[3];
    const float* Wh     = (const float*)d_in[4];
    const float* bh     = (const float*)d_in[5];
    const float* Wqk    = (const float*)d_in[6];
    const float* bqk    = (const float*)d_in[7];
    const float* gamma  = (const float*)d_in[8];
    const float* beta   = (const float*)d_in[9];
    const float* rel_emb= (const float*)d_in[10];
    const float* Wout   = (const float*)d_in[11];
    const float* bout   = (const float*)d_in[12];
    float* out = (float*)d_out;
    float* ws  = (float*)d_ws;

    // workspace layout (float offsets; all 16B-aligned)
    float* gateT  = ws;                            //  6,000,000 f
    float* bias   = ws + 6000000;                  //    250,000 f
    u16*   nxb    = (u16*)(ws + 6250000);          // 10000x320 u16
    u16*   WhT    = (u16*)(ws + 7850000);          //  1200x320 u16
    u16*   Wqkb   = (u16*)(ws + 8042000);          //   128x320 u16
    u16*   WoutT  = (u16*)(ws + 8062480);          //   300x608 u16
    u16*   qb     = (u16*)(ws + 8153680);          // 10000x128 u16
    u16*   kb     = (u16*)(ws + 8793680);          // 10000x128 u16
    u16*   attnb  = (u16*)(ws + 9433680);          // 20x500x512 u16
    u16*   vT     = (u16*)(ws + 11993680);         // 20x640x512 u16
    u16*   gatedb = (u16*)(ws + 15270480);         // 10000x608 u16
    int*   hist   = (int*)(ws + 21310480);         // 20 x 256-int stride
    unsigned* gmaxu = (unsigned*)(ws + 21315600);  // 20 x 64-uint stride
    int*   counts = (int*)(ws + 21316880);         //   240,000
    int*   h2cm   = (int*)(ws + 21556880);         // h2 20x32 + cmax 20x32

    // 1. prep + LN; also zeroes hist/gmaxu/h2cm
    prep_ln_kernel<<<5880, 256, 0, stream>>>(x, ln_g, ln_b, nxb, Wh, Wqk, Wout,
                                             rel_emb, WhT, Wqkb, WoutT, bias,
                                             hist, gmaxu, h2cm);

    // 2. MERGED: qk gemm + silu/rotary (M=10000,N=128,Kp=320; 320 blocks)
    //    || h gemm -> vT bf16 + gateT fp32 + fused hist/gmax
    //    (M=1200,N=10000,Kp=320; 3040 blocks)
    gemm_qk_h<<<3360, 256, 32768, stream>>>(
        nxb, Wqkb, WhT,
        EpiQKRot{bqk, gamma, beta, qb, kb},
        EpiH{bh, vT, gateT, hist, gmaxu});

    // 3. MERGED: scores -> attnb bf16 (batch b -> XCD b%8; 1536 blocks)
    //    || counts + h2/cmax accumulation (940 blocks)
    gemm_sc<<<2476, 256, 32768, stream>>>(
        qb, kb, EpiAttnB{bias, mask2, attnb},
        gateT, hist, gmaxu, counts, h2cm);

    // 4. attn@v + fused gate mask (per batch 500x640, Kp=512): batch b -> XCD
    //    b%8 (same pin as scores -> attnb + gateT[b] read from this XCD's L2);
    //    t2[b] derived per-thread in epi.init from h2cm
    gemm_nb<0><<<8 * 10 * 8 * 3, 256, 0, stream>>>(
        attnb, vT, 512, 512, 512,
        (long)SS * 512, (long)640 * 512, 10, 8, BB,
        EpiGateN{gateT, counts, h2cm, gatedb});

    // 5. out = gated@Wout + bout + x (M=10000, N=300, Kp=608):
    //    slice M over XCDs, TX=5 n-tiles
    gemm_nb<2><<<8 * 5 * 20, 256, 0, stream>>>(
        gatedb, WoutT, 608, 608, 608, 0L, 0L, 5, 20, 157, EpiOutB{bout, x, out});
}

// Round 4
// 212.021 us; speedup vs baseline: 1.4066x; 1.0811x over previous
//
#include <hip/hip_runtime.h>
#include <hip/hip_bf16.h>

#define BB 20
#define SS 500
#define DIMD 300
#define HIDH 600
#define QKD 128

typedef unsigned short u16;
typedef __attribute__((ext_vector_type(8))) __bf16 bf16x8;
typedef __attribute__((ext_vector_type(8))) short short8;
typedef __attribute__((ext_vector_type(4))) float floatx4;

__device__ __forceinline__ u16 f2bu(float f) {
    __hip_bfloat16 h = __float2bfloat16(f);
    return *reinterpret_cast<u16*>(&h);
}
__device__ __forceinline__ float bu2f(u16 u) {
    unsigned v = ((unsigned)u) << 16;
    return __uint_as_float(v);
}

__device__ __forceinline__ floatx4 mfma_bf16(short8 a, short8 b, floatx4 c) {
    return __builtin_amdgcn_mfma_f32_16x16x32_bf16(
        __builtin_bit_cast(bf16x8, a), __builtin_bit_cast(bf16x8, b), c, 0, 0, 0);
}

// async global->LDS, 16B/lane; LDS dest = wave-uniform base + lane*16
__device__ __forceinline__ void glds16(const u16* g, u16* l) {
    __builtin_amdgcn_global_load_lds(
        (__attribute__((address_space(1))) const void*)g,
        (__attribute__((address_space(3))) void*)l, 16, 0, 0);
}

__device__ __forceinline__ unsigned fenc(float m) {
    unsigned bits = __float_as_uint(m);
    return (bits & 0x80000000u) ? ~bits : (bits | 0x80000000u);
}

// ---------------- merged prep + LayerNorm/shift ----------------
__global__ __launch_bounds__(256)
void prep_ln_kernel(const float* __restrict__ x, const float* __restrict__ lng,
                    const float* __restrict__ lnb, u16* __restrict__ nxb,
                    const float* __restrict__ Wh, const float* __restrict__ Wqk,
                    const float* __restrict__ Wout, const float* __restrict__ rel_emb,
                    u16* __restrict__ WhT, u16* __restrict__ Wqkb,
                    u16* __restrict__ WoutT, float* __restrict__ bias,
                    int* __restrict__ hist, unsigned* __restrict__ gmaxu,
                    int* __restrict__ h2cm) {
    long id = (long)blockIdx.x * 256 + threadIdx.x;
    if (id < 640000) {                        // LayerNorm + shift, one wave per row
        int bs = id >> 6;
        int t = id & 63;
        int s = bs % SS;
        const float* xr = x + (long)bs * DIMD;
        float sum = 0.f, sq = 0.f;
        for (int d = t; d < DIMD; d += 64) { float v = xr[d]; sum += v; sq += v * v; }
        for (int off = 1; off < 64; off <<= 1) {
            sum += __shfl_xor(sum, off);
            sq  += __shfl_xor(sq, off);
        }
        float mean = sum * (1.f / DIMD);
        float var  = sq * (1.f / DIMD) - mean * mean;
        float rstd = rsqrtf(var + 1e-5f);
        for (int d = t; d < DIMD; d += 64) {
            float nv = (xr[d] - mean) * rstd * lng[d] + lnb[d];
            if (d < DIMD / 2) {
                if (s < SS - 1) nxb[(long)(bs + 1) * 320 + d] = f2bu(nv);
            } else {
                nxb[(long)bs * 320 + d] = f2bu(nv);
            }
        }
        if (s == 0)
            for (int d = t; d < DIMD / 2; d += 64) nxb[(long)bs * 320 + d] = 0;
        for (int d = DIMD + t; d < 320; d += 64) nxb[(long)bs * 320 + d] = 0;
        return;
    }
    id -= 640000;
    if (id < 384000) {                        // WhT[n][k], k<320
        int k = id / 1200, n = id - (long)k * 1200;
        WhT[(long)n * 320 + k] = (k < 300) ? f2bu(Wh[(long)k * 1200 + n]) : (u16)0;
        return;
    }
    id -= 384000;
    if (id < 40960) {                         // Wqkb[n][k]
        int k = id / 128, n = id - (long)k * 128;
        Wqkb[(long)n * 320 + k] = (k < 300) ? f2bu(Wqk[(long)k * 128 + n]) : (u16)0;
        return;
    }
    id -= 40960;
    if (id < 182400) {                        // WoutT[n][k], k<608
        int k = id / 300, n = id - (long)k * 300;
        WoutT[(long)n * 608 + k] = (k < 600) ? f2bu(Wout[(long)k * 300 + n]) : (u16)0;
        return;
    }
    id -= 182400;
    if (id < 250000) {                        // T5 bias 500x500
        int i = id / 500, j = id - (long)i * 500;
        int n = i - j;
        int ret = (n < 0) ? 16 : 0;
        int na = n < 0 ? -n : n;
        int bucket;
        if (na < 8) bucket = ret + na;
        else {
            int vil = 8 + (int)(logf((float)na * 0.125f) / logf(16.f) * 8.f);
            vil = vil < 15 ? vil : 15;
            bucket = ret + vil;
        }
        bias[id] = rel_emb[bucket] * 11.313708498984761f;
        return;
    }
    id -= 250000;
    if (id < 5120) { hist[id] = 0; return; }   // 20 batches x 256-int stride
    id -= 5120;
    if (id < 1280) { gmaxu[id] = 0u; return; } // 20 batches x 64-uint stride
    id -= 1280;
    if (id < 1280) h2cm[(int)id] = 0;          // h2 hist (20x32) + cmax (20x32)
}

// ---------------- Epilogues ----------------
// All epilogues implement: init(bz) pre-K-loop hook, operator()(acc,bz,m,n,j)
// with j = compile-time n-subtile slot (0/1), finish(bz,m0,n0) post hook.

// EpiH: gemm1 transposed (m = hidden [0,1200), n = token [0,10000)).
// Fuses gate stats (saves re-reading 24MB of gateT):
//   - hist: |g|>=1 is a ~4-sigma tail -> a few hundred atomics total.
//   - gmax: per-lane running max per STATIC n-slot (R2 lesson: per-call
//     column tracking serialized the unrolled epilogue; slot j is compile
//     time).  Column groups are 16-aligned, 10000%16==0 -> group validity
//     and (usually) batch are wave-uniform; straddling groups (500%16!=0)
//     fall back to per-column atomics from lanes 0..15.
struct EpiH {
    const float* bh; u16* vT; float* gateT; int* hist; unsigned* gmaxu;
    float gm0 = -1e30f, gm1 = -1e30f;
    __device__ void init(int) {}
    __device__ void operator()(float acc, int bz, int m, int n, int j) {
        if (m >= 1200 || n >= 10000) return;
        float v = acc + bh[m];
        v = v / (1.f + expf(-v));
        int b = n / SS, s = n - b * SS;
        if (m < HIDH) { vT[((long)b * 640 + m) * 512 + s] = f2bu(v); return; }
        gateT[((long)b * HIDH + (m - HIDH)) * SS + s] = v;
        if (j) gm1 = fmaxf(gm1, v); else gm0 = fmaxf(gm0, v);
        float ag = fabsf(v);
        if (ag >= 1.f) {
            int bin = (int)fminf(floorf(ag), 128.f);
            atomicAdd(&hist[b * 256 + bin], 1);
        }
    }
    __device__ void flushS(float m, int base) {
        if (base >= 10000) return;
        m = fmaxf(m, __shfl_xor(m, 16));       // reduce over l4 (same column)
        m = fmaxf(m, __shfl_xor(m, 32));
        int b0 = base / SS;
        if (b0 == (base + 15) / SS) {          // batch-uniform column group
            m = fmaxf(m, __shfl_xor(m, 1));
            m = fmaxf(m, __shfl_xor(m, 2));
            m = fmaxf(m, __shfl_xor(m, 4));
            m = fmaxf(m, __shfl_xor(m, 8));
            if ((threadIdx.x & 63) == 0 && m > -1e29f)
                atomicMax(&gmaxu[b0 * 64], fenc(m));
        } else {                               // group straddles batch edge
            int l = threadIdx.x & 63;
            if (l < 16 && m > -1e29f)
                atomicMax(&gmaxu[((base + l) / SS) * 64], fenc(m));
        }
    }
    __device__ void finish(int bz, int m0, int n0) {
        if (m0 + 32 <= 600) return;            // wave has no gate rows
        flushS(gm0, n0);
        flushS(gm1, n0 + 16);
    }
};
struct EpiQKRot {        // qk + silu + gamma/beta + rotary (NO early return: shuffles)
    const float* bqk; const float* gamma; const float* beta;
    u16* qb; u16* kb;
    __device__ void init(int) const {}
    __device__ void operator()(float acc, int bz, int m, int n, int j) const {
        float v = acc + bqk[n];
        v = v / (1.f + expf(-v));
        float qp = v * gamma[n] + beta[n];
        float kp = v * gamma[QKD + n] + beta[QKD + n];
        float qx = __shfl_xor(qp, 1);
        float kx = __shfl_xor(kp, 1);
        float qo = qp, ko = kp;
        if (n < 32) {
            int s = m % SS;
            float inv = expf(-(float)(n & ~1) * (logf(10000.f) / 32.f));
            float ang = (float)s * inv;
            float c, sn;
            sincosf(ang, &sn, &c);
            float qr = (n & 1) ? qx : -qx;
            float kr = (n & 1) ? kx : -kx;
            qo = qp * c + qr * sn;
            ko = kp * c + kr * sn;
        }
        if (m < 10000) {
            qb[(long)m * QKD + n] = f2bu(qo);
            kb[(long)m * QKD + n] = f2bu(ko);
        }
    }
    __device__ void finish(int, int, int) const {}
};
struct EpiAttnB {        // scores -> (relu((s+bias)/S))^2 * mask -> bf16 [500][512]
    const float* bias; const float* mask; u16* attnb;
    __device__ void init(int) const {}
    __device__ void operator()(float acc, int b, int m, int n, int j) const {
        if (m >= SS || n >= 512) return;
        float r = 0.f;
        if (n < SS) {
            float s = (acc + bias[m * SS + n]) * (1.f / (float)SS);
            s = fmaxf(s, 0.f);
            r = s * s * mask[m * SS + n];
        }
        attnb[((long)b * SS + m) * 512 + n] = f2bu(r);
    }
    __device__ void finish(int, int, int) const {}
};
struct EpiGateN {        // gated = gm * (attn@v) * gate -> bf16 [10000][608]
    // reads gateT fp32 directly (batch slice is 1.2MB, L2-resident on the
    // XCD this batch is pinned to).  t2[b] computed per-thread in init()
    // from the global h2-hist/cmax accumulated by counts blocks.
    const float* gateT; const int* counts; const int* h2cm; u16* gated;
    int t2 = 0;
    __device__ void init(int b) {
        int cmax = h2cm[640 + b * 32];
        int suffix = 0, best = 0;
        bool found = false;
        for (int tt = 16; tt >= 1; --tt) {
            suffix += h2cm[b * 32 + tt];
            if (!found && tt <= cmax && suffix > 3600) { best = tt; found = true; }
        }
        t2 = found ? best : cmax;
    }
    __device__ void operator()(float acc, int b, int m, int n, int j) const {
        if (m >= SS || n >= 608) return;
        float r = 0.f;
        if (n < HIDH) {
            float g = gateT[((long)b * HIDH + n) * SS + m];
            int c = counts[(b * 100 + m / 5) * 120 + n / 5];
            float bv = (c >= t2) ? 1.f : 0.25f;
            float p = ((m % 5) == 4 || (n % 5) == 4) ? 0.f : 1.f;
            r = acc * g * bv * p;
        }
        gated[((long)(b * SS + m)) * 608 + n] = f2bu(r);
    }
    __device__ void finish(int, int, int) const {}
};
struct EpiOutB {         // out = gated@Wout + bout + x
    const float* bout; const float* x; float* out;
    __device__ void init(int) const {}
    __device__ void operator()(float acc, int b, int m, int n, int j) const {
        if (m >= 10000 || n >= DIMD) return;
        out[(long)m * DIMD + n] = acc + bout[n] + x[(long)m * DIMD + n];
    }
    __device__ void finish(int, int, int) const {}
};

// ---------------- cooperative-staged bf16 MFMA GEMM body ----------------
// C[M,N] = A[M,Kp] * Bt[N,Kp]^T.  Block 64x64 = 4 waves in 2x2 (each wave
// computes a 32x32 tile).  R4 structure: BLOCK-SHARED staging with a 3-deep
// rotating buffer (vs R3's per-wave double buffer):
//   - buffer = [128 rows][32 k] u16 (rows 0..63 = A-tile, 64..127 = B-tile),
//     8KB; 3 buffers = 24KB/block -> 6 blocks/CU = 24 waves/CU cap (R3's
//     32KB -> 5 blocks; and staging was DUPLICATED 2x across wave pairs).
//   - waves 0,1 stage A rows, waves 2,3 stage B rows: 2 glds/wave/step.
//   - prefetch distance 2: the glds issued at step k lands at step k+2 ->
//     ~2 iterations (~200-300cy) of latency cover vs R3's ~1 (~100cy).
// Sync per step: s_waitcnt vmcnt(2) lgkmcnt(0)  (retire THIS buffer's own 2
// loads, keep next buffer's in flight; lgkmcnt(0) ensures this wave's prior
// ds_reads are complete before passing the barrier) then RAW s_barrier (no
// compiler vmcnt(0) drain), then compiler fence so ds_reads can't hoist
// above the barrier (rule-18 analog).  Overwrite safety: buffer j is reused
// by the glds issued AFTER barrier j+1, and every wave finished reading
// buffer j (lgkmcnt(0)) before arriving at barrier j+1.
// 1-D grid with XCD pinning (workgroup->XCD is round-robin on linear id).
// MODE 0: batch g -> XCD g%8.  MODE 1: slice N per-XCD (TX groups).
// MODE 2: slice M per-XCD (TY groups).  Early whole-block return is safe
// (uniform, before any barrier).  Staging has NO bounds checks: overruns
// read adjacent ws buffers; NaN garbage only poisons acc rows/cols whose
// epilogue writes are guarded off; K-pads are real zeros.
template<int MODE, class Epi>
__device__ __forceinline__ void gemm_body(
        int lin, u16* __restrict__ S,
        const u16* __restrict__ A, const u16* __restrict__ Bt,
        int Kp, int lda, int ldb, long sA, long sB,
        int TX, int TY, int bound, Epi epi) {
    int xcd = lin & 7, i = lin >> 3;
    int per = TX * TY;
    int w = i / per;
    int tl = i - w * per;
    int g = xcd + (w << 3);
    int tx = tl % TX, ty = tl / TX;
    int bx, by, bz;
    if (MODE == 0)      { if (g >= bound) return; bx = tx; by = ty; bz = g; }
    else if (MODE == 1) { bx = g * TX + tx; if (bx >= bound) return; by = ty; bz = 0; }
    else                { by = g * TY + ty; if (by >= bound) return; bx = tx; bz = 0; }

    A += (long)bz * sA; Bt += (long)bz * sB;
    int t = threadIdx.x, lane = t & 63, wave = t >> 6;
    int l15 = lane & 15, l4 = lane >> 4;
    int mw = (wave >> 1) << 5, nw = (wave & 1) << 5;
    int m0 = (by << 6) + mw;
    int n0 = (bx << 6) + nw;

    epi.init(bz);

    // staging assignment: waves 0,1 -> A rows [w*32,w*32+32); waves 2,3 -> B
    int srow = lane >> 2, scol = (lane & 3) << 3;
    const u16* gp0;
    int drow;
    if (wave < 2) {
        gp0 = A + (long)((by << 6) + (wave << 5) + srow) * lda + scol;
        gp0 += 0;
        drow = wave << 5;
    } else {
        gp0 = Bt + (long)((bx << 6) + ((wave - 2) << 5) + srow) * ldb + scol;
        drow = 64 + ((wave - 2) << 5);
    }
    const u16* gp1 = gp0 + (long)16 * (wave < 2 ? lda : ldb);
    u16* d0 = S + drow * 32;
    u16* d1 = S + (drow + 16) * 32;

    floatx4 acc[2][2];
#pragma unroll
    for (int i2 = 0; i2 < 2; ++i2)
#pragma unroll
        for (int j = 0; j < 2; ++j) acc[i2][j] = (floatx4){0.f, 0.f, 0.f, 0.f};

    int nsteps = Kp >> 5;
    // prologue: stage buffers 0 and 1 (2+2 outstanding per wave)
    glds16(gp0, d0);
    glds16(gp1, d1);
    if (nsteps > 1) {
        glds16(gp0 + 32, d0 + 4096);
        glds16(gp1 + 32, d1 + 4096);
    }

    int bufc = 0;                              // current buffer index (si % 3)
    for (int si = 0; si < nsteps; ++si) {
        if (si + 1 < nsteps)
            asm volatile("s_waitcnt vmcnt(2) lgkmcnt(0)" ::: "memory");
        else
            asm volatile("s_waitcnt vmcnt(0) lgkmcnt(0)" ::: "memory");
        __builtin_amdgcn_s_barrier();
        asm volatile("" ::: "memory");         // pin ds_reads below barrier
        int kn = (si + 2) << 5;
        if (kn < Kp) {                         // prefetch distance 2
            int bufp = (bufc == 0) ? 2 : bufc - 1;   // (si+2)%3
            glds16(gp0 + kn, d0 + bufp * 4096);
            glds16(gp1 + kn, d1 + bufp * 4096);
        }
        const u16* SB = S + bufc * 4096;
        short8 a0 = *(const short8*)(SB + ((mw + l15) << 5) + (l4 << 3));
        short8 a1 = *(const short8*)(SB + ((mw + 16 + l15) << 5) + (l4 << 3));
        short8 b0 = *(const short8*)(SB + ((64 + nw + l15) << 5) + (l4 << 3));
        short8 b1 = *(const short8*)(SB + ((64 + nw + 16 + l15) << 5) + (l4 << 3));
        acc[0][0] = mfma_bf16(a0, b0, acc[0][0]);
        acc[0][1] = mfma_bf16(a0, b1, acc[0][1]);
        acc[1][0] = mfma_bf16(a1, b0, acc[1][0]);
        acc[1][1] = mfma_bf16(a1, b1, acc[1][1]);
        bufc = (bufc == 2) ? 0 : bufc + 1;
    }
#pragma unroll
    for (int i2 = 0; i2 < 2; ++i2) {
        int bm = m0 + (i2 << 4) + (l4 << 2);
#pragma unroll
        for (int j = 0; j < 2; ++j) {
            int bn = n0 + (j << 4) + l15;
#pragma unroll
            for (int r = 0; r < 4; ++r)
                epi(acc[i2][j][r], bz, bm + r, bn, j);
        }
    }
    epi.finish(bz, m0, n0);
}

// standalone wrapper (static LDS, 24KB)
template<int MODE, class Epi>
__global__ __launch_bounds__(256)
void gemm_nb(const u16* __restrict__ A, const u16* __restrict__ Bt,
             int Kp, int lda, int ldb, long sA, long sB,
             int TX, int TY, int bound, Epi epi) {
    __shared__ __align__(16) u16 S[3 * 4096];
    gemm_body<MODE>(blockIdx.x, S, A, Bt, Kp, lda, ldb, sA, sB, TX, TY, bound, epi);
}

// merged qk-gemm (blocks [0,320)) + h-gemm (blocks [320,3360)).  Independent,
// both read nxb, both latency-bound -> overlap in one launch.  Offset
// 320%8==0 preserves the h-gemm's XCD slicing.  Dynamic LDS (24KB).
__global__ __launch_bounds__(256)
void gemm_qk_h(const u16* __restrict__ nxb, const u16* __restrict__ Wqkb,
               const u16* __restrict__ WhT, EpiQKRot eq, EpiH eh) {
    extern __shared__ u16 S[];
    int lin = blockIdx.x;
    if (lin < 320)
        gemm_body<2>(lin, S, nxb, Wqkb, 320, 320, 320, 0L, 0L, 2, 20, 157, eq);
    else
        gemm_body<1>(lin - 320, S, WhT, nxb, 320, 320, 320, 0L, 0L, 20, 19, 157, eh);
}

// merged scores-gemm (blocks [0,1536)) + counts (blocks [1536,2476)).
// counts: 47 blocks per batch; per-block LDS h2-hist + max, one global
// atomicAdd per bin per block into h2cm (hist 20x32 @0, cmax 20x32 @640).
__global__ __launch_bounds__(256)
void gemm_sc(const u16* __restrict__ qb, const u16* __restrict__ kb, EpiAttnB ea,
             const float* __restrict__ gateT, const int* __restrict__ hist,
             const unsigned* __restrict__ gmaxu, int* __restrict__ counts,
             int* __restrict__ h2cm) {
    extern __shared__ u16 S[];
    int lin = blockIdx.x;
    if (lin < 1536) {
        gemm_body<0>(lin, S, qb, kb, QKD, QKD, QKD,
                     (long)SS * QKD, (long)SS * QKD, 8, 8, BB, ea);
        return;
    }
    int cb = lin - 1536;
    int b = cb / 47, blk = cb - b * 47;
    int r = blk * 256 + threadIdx.x;
    int* h2l = (int*)S;
    int* smaxp = h2l + 17;
    if (threadIdx.x < 17) h2l[threadIdx.x] = 0;
    if (threadIdx.x == 0) *smaxp = 0;
    __syncthreads();
    int c = 0;
    if (r < 12000) {
        unsigned enc = gmaxu[b * 64];
        unsigned bits = (enc & 0x80000000u) ? (enc & 0x7FFFFFFFu) : ~enc;
        float gmax = floorf(__uint_as_float(bits));
        int suffix = 0, trim = 1;
        for (int tt = 128; tt >= 1; --tt) {
            suffix += hist[b * 256 + tt];
            if ((float)tt <= gmax && suffix > 90000) { trim = tt; break; }
        }
        float tr = (float)trim;
        int bi = r / 120, bj = r - bi * 120;
        const float* gb = gateT + (long)b * SS * HIDH;
#pragma unroll
        for (int cc = 0; cc < 4; ++cc)
#pragma unroll
            for (int rr = 0; rr < 4; ++rr) {
                float gv = gb[(long)(bj * 5 + cc) * SS + bi * 5 + rr];
                c += (fabsf(gv) >= tr) ? 1 : 0;
            }
        counts[b * 12000 + r] = c;
        if (c) atomicAdd(&h2l[c], 1);
    }
    int lmax = c;
    for (int off = 32; off; off >>= 1) {
        int o = __shfl_xor(lmax, off);
        lmax = lmax > o ? lmax : o;
    }
    if ((threadIdx.x & 63) == 0) atomicMax(smaxp, lmax);
    __syncthreads();
    if (threadIdx.x < 17 && h2l[threadIdx.x])
        atomicAdd(&h2cm[b * 32 + threadIdx.x], h2l[threadIdx.x]);
    if (threadIdx.x == 0) atomicMax(&h2cm[640 + b * 32], *smaxp);
}

extern "C" void kernel_launch(void* const* d_in, const int* in_sizes, int n_in,
                              void* d_out, int out_size, void* d_ws, size_t ws_size,
                              hipStream_t stream) {
    const float* x      = (const float*)d_in[0];
    const float* mask2  = (const float*)d_in[1];
    const float* ln_g   = (const float*)d_in[2];
    const float* ln_b   = (const float*)d_in[3];
    const float* Wh     = (const float*)d_in[4];
    const float* bh     = (const float*)d_in[5];
    const float* Wqk    = (const float*)d_in[6];
    const float* bqk    = (const float*)d_in[7];
    const float* gamma  = (const float*)d_in[8];
    const float* beta   = (const float*)d_in[9];
    const float* rel_emb= (const float*)d_in[10];
    const float* Wout   = (const float*)d_in[11];
    const float* bout   = (const float*)d_in[12];
    float* out = (float*)d_out;
    float* ws  = (float*)d_ws;

    // workspace layout (float offsets; all 16B-aligned)
    float* gateT  = ws;                            //  6,000,000 f
    float* bias   = ws + 6000000;                  //    250,000 f
    u16*   nxb    = (u16*)(ws + 6250000);          // 10000x320 u16
    u16*   WhT    = (u16*)(ws + 7850000);          //  1200x320 u16
    u16*   Wqkb   = (u16*)(ws + 8042000);          //   128x320 u16
    u16*   WoutT  = (u16*)(ws + 8062480);          //   300x608 u16
    u16*   qb     = (u16*)(ws + 8153680);          // 10000x128 u16
    u16*   kb     = (u16*)(ws + 8793680);          // 10000x128 u16
    u16*   attnb  = (u16*)(ws + 9433680);          // 20x500x512 u16
    u16*   vT     = (u16*)(ws + 11993680);         // 20x640x512 u16
    u16*   gatedb = (u16*)(ws + 15270480);         // 10000x608 u16
    int*   hist   = (int*)(ws + 21310480);         // 20 x 256-int stride
    unsigned* gmaxu = (unsigned*)(ws + 21315600);  // 20 x 64-uint stride
    int*   counts = (int*)(ws + 21316880);         //   240,000
    int*   h2cm   = (int*)(ws + 21556880);         // h2 20x32 + cmax 20x32

    // 1. prep + LN; also zeroes hist/gmaxu/h2cm
    prep_ln_kernel<<<5880, 256, 0, stream>>>(x, ln_g, ln_b, nxb, Wh, Wqk, Wout,
                                             rel_emb, WhT, Wqkb, WoutT, bias,
                                             hist, gmaxu, h2cm);

    // 2. MERGED: qk gemm + silu/rotary (M=10000,N=128,Kp=320; 320 blocks)
    //    || h gemm -> vT bf16 + gateT fp32 + fused hist/gmax
    //    (M=1200,N=10000,Kp=320; 3040 blocks)
    gemm_qk_h<<<3360, 256, 24576, stream>>>(
        nxb, Wqkb, WhT,
        EpiQKRot{bqk, gamma, beta, qb, kb},
        EpiH{bh, vT, gateT, hist, gmaxu});

    // 3. MERGED: scores -> attnb bf16 (batch b -> XCD b%8; 1536 blocks)
    //    || counts + h2/cmax accumulation (940 blocks)
    gemm_sc<<<2476, 256, 24576, stream>>>(
        qb, kb, EpiAttnB{bias, mask2, attnb},
        gateT, hist, gmaxu, counts, h2cm);

    // 4. attn@v + fused gate mask (per batch 500x640, Kp=512): batch b -> XCD
    //    b%8 (same pin as scores -> attnb + gateT[b] read from this XCD's L2);
    //    t2[b] derived per-thread in epi.init from h2cm
    gemm_nb<0><<<8 * 10 * 8 * 3, 256, 0, stream>>>(
        attnb, vT, 512, 512, 512,
        (long)SS * 512, (long)640 * 512, 10, 8, BB,
        EpiGateN{gateT, counts, h2cm, gatedb});

    // 5. out = gated@Wout + bout + x (M=10000, N=300, Kp=608):
    //    slice M over XCDs, TX=5 n-tiles
    gemm_nb<2><<<8 * 5 * 20, 256, 0, stream>>>(
        gatedb, WoutT, 608, 608, 608, 0L, 0L, 5, 20, 157, EpiOutB{bout, x, out});
}